// Round 1
// 670.806 us; speedup vs baseline: 1.0110x; 1.0110x over previous
//
#include <hip/hip_runtime.h>
#include <hip/hip_bf16.h>

typedef unsigned short u16;
typedef unsigned int u32;
typedef __attribute__((ext_vector_type(8))) short short8;
typedef __attribute__((ext_vector_type(4))) float f32x4;

__device__ __forceinline__ u16 f2bf(float x) {
  __hip_bfloat16 h = __float2bfloat16(x);
  return *reinterpret_cast<u16*>(&h);
}
__device__ __forceinline__ float bflo(u32 u) { return __uint_as_float(u << 16); }
__device__ __forceinline__ float bfhi(u32 u) { return __uint_as_float(u & 0xffff0000u); }

// ---------------- weight transpose + cast: dst[n*K+k] = bf16(src[k*N+n]) ----------------
__global__ void k_wprep(const float* __restrict__ src, u16* __restrict__ dst, int K, int N) {
  int idx = blockIdx.x * 256 + threadIdx.x;
  if (idx >= K * N) return;
  int k = idx / N, n = idx - k * N;
  dst[n * K + k] = f2bf(src[idx]);
}

// ---------------- LN1 + roll(-2) + window partition -> bf16 [262144][128] ----------------
__global__ __launch_bounds__(256) void k_ln1(const float* __restrict__ in,
                                             const float* __restrict__ g1,
                                             const float* __restrict__ b1,
                                             u16* __restrict__ lnb) {
  int lane = threadIdx.x & 63;
  size_t o = (size_t)blockIdx.x * 4 + (threadIdx.x >> 6);
  int n = (int)(o & 63), wbox = (int)((o >> 6) & 511), b = (int)(o >> 15);
  int gx = wbox >> 6, gy = (wbox >> 3) & 7, gz = wbox & 7;
  int ix = n >> 4, iy = (n >> 2) & 3, iz = n & 3;
  int X = (gx * 4 + ix + 2) & 31, Y = (gy * 4 + iy + 2) & 31, Z = (gz * 4 + iz + 2) & 31;
  const float* row = in + (((size_t)b << 15) + (size_t)(X * 1024 + Y * 32 + Z)) * 128;
  float x0 = row[lane], x1 = row[lane + 64];
  float s = x0 + x1, ss = x0 * x0 + x1 * x1;
  #pragma unroll
  for (int off = 32; off > 0; off >>= 1) {
    s += __shfl_xor(s, off, 64);
    ss += __shfl_xor(ss, off, 64);
  }
  float mean = s * 0.0078125f;
  float var = ss * 0.0078125f - mean * mean;
  float rs = rsqrtf(var + 1e-5f);
  lnb[o * 128 + lane]      = f2bf((x0 - mean) * rs * g1[lane] + b1[lane]);
  lnb[o * 128 + lane + 64] = f2bf((x1 - mean) * rs * g1[lane + 64] + b1[lane + 64]);
}

// ---------------- shared 64x128-tile MFMA core: A_s [64][136], B_s(=W^T) [128][136] ----------------
__device__ __forceinline__ void mfma_64x128(const u16* A_s, const u16* B_s,
                                            f32x4 acc[2][4], int wid, int lane) {
  const int m = lane & 15, kg = lane >> 4;
  const int ro = (wid & 1) * 32, co = (wid >> 1) * 64;
  #pragma unroll
  for (int kc = 0; kc < 4; ++kc) {
    short8 a[2], b[4];
    #pragma unroll
    for (int tm = 0; tm < 2; ++tm)
      a[tm] = *(const short8*)(A_s + (ro + tm * 16 + m) * 136 + kc * 32 + kg * 8);
    #pragma unroll
    for (int tn = 0; tn < 4; ++tn)
      b[tn] = *(const short8*)(B_s + (co + tn * 16 + m) * 136 + kc * 32 + kg * 8);
    #pragma unroll
    for (int tm = 0; tm < 2; ++tm)
      #pragma unroll
      for (int tn = 0; tn < 4; ++tn)
        acc[tm][tn] = __builtin_amdgcn_mfma_f32_16x16x32_bf16(a[tm], b[tn], acc[tm][tn], 0, 0, 0);
  }
}

// ---------------- QKV GEMM: [T,128] x [128,384] -> bf16 qkv [T][384], q pre-scaled ----------------
__global__ __launch_bounds__(256) void k_qkv(const u16* __restrict__ lnb,
                                             const u16* __restrict__ wT,
                                             u16* __restrict__ qkv) {
  __shared__ __align__(16) u16 A_s[64 * 136];
  __shared__ __align__(16) u16 B_s[128 * 136];
  const int t = threadIdx.x, wid = t >> 6, lane = t & 63;
  const size_t mbase = (size_t)blockIdx.x * 64;
  const int n0 = blockIdx.y * 128;
  {
    int r = t >> 2, seg = t & 3;
    const short8* src = (const short8*)(lnb + (mbase + r) * 128 + seg * 32);
    short8* dst = (short8*)(A_s + r * 136 + seg * 32);
    #pragma unroll
    for (int i = 0; i < 4; ++i) dst[i] = src[i];
  }
  {
    int r = t >> 1, half = t & 1;
    const short8* src = (const short8*)(wT + (size_t)(n0 + r) * 128 + half * 64);
    short8* dst = (short8*)(B_s + r * 136 + half * 64);
    #pragma unroll
    for (int i = 0; i < 8; ++i) dst[i] = src[i];
  }
  __syncthreads();
  f32x4 zero = {0.f, 0.f, 0.f, 0.f};
  f32x4 acc[2][4];
  #pragma unroll
  for (int tm = 0; tm < 2; ++tm)
    #pragma unroll
    for (int tn = 0; tn < 4; ++tn) acc[tm][tn] = zero;
  mfma_64x128(A_s, B_s, acc, wid, lane);
  const int m = lane & 15, kg = lane >> 4;
  const int ro = (wid & 1) * 32, co = (wid >> 1) * 64;
  #pragma unroll
  for (int tm = 0; tm < 2; ++tm)
    #pragma unroll
    for (int tn = 0; tn < 4; ++tn)
      #pragma unroll
      for (int r = 0; r < 4; ++r) {
        int row = ro + tm * 16 + kg * 4 + r;
        int cc = n0 + co + tn * 16 + m;
        float v = acc[tm][tn][r];
        if (cc < 128) v *= 0.17677669529663687f;   // q * HD^-0.5
        qkv[(mbase + row) * 384 + cc] = f2bf(v);
      }
}

// ---------------- per-window attention, MFMA version: block=window, wave=head ----------------
__global__ __launch_bounds__(256) void k_attn(const u16* __restrict__ qkv,
                                              const float* __restrict__ btab,
                                              u16* __restrict__ att) {
  __shared__ float bias_s[4][128];               // [h][121] transposed bias table
  __shared__ __align__(16) u16 Vt_s[4][32][72];  // V^T per head: [d][key]
  __shared__ __align__(16) u16 P_s[4][64][72];   // exp(S-m) per head, unnormalized
  const int t = threadIdx.x;
  const int wv = t >> 6, lane = t & 63;
  const int m = lane & 15, q4 = lane >> 4;
  const int bw = blockIdx.x;
  const size_t base = (size_t)bw * 64;
  const int wbox = bw & 511;
  const int gx = wbox >> 6, gy = (wbox >> 3) & 7, gz = wbox & 7;

  for (int i = t; i < 484; i += 256) bias_s[i & 3][i >> 2] = btab[i];
  #pragma unroll
  for (int i = 0; i < 16; ++i) {
    int nn = i * 4 + wv;
    int ch = lane * 2;
    int hh = ch >> 5, d = ch & 31;
    u32 vv = *(const u32*)(qkv + (base + nn) * 384 + 256 + ch);
    Vt_s[hh][d][nn]     = (u16)(vv & 0xffffu);
    Vt_s[hh][d + 1][nn] = (u16)(vv >> 16);
  }

  short8 qf[4], kf[4];
  #pragma unroll
  for (int ti = 0; ti < 4; ++ti) {
    qf[ti] = *(const short8*)(qkv + (base + ti * 16 + m) * 384 + wv * 32 + q4 * 8);
    kf[ti] = *(const short8*)(qkv + (base + ti * 16 + m) * 384 + 128 + wv * 32 + q4 * 8);
  }

  f32x4 zero = {0.f, 0.f, 0.f, 0.f};
  f32x4 S[4][4];
  #pragma unroll
  for (int ti = 0; ti < 4; ++ti)
    #pragma unroll
    for (int tj = 0; tj < 4; ++tj) S[ti][tj] = zero;

  __syncthreads();

  #pragma unroll
  for (int ti = 0; ti < 4; ++ti)
    #pragma unroll
    for (int tj = 0; tj < 4; ++tj)
      S[ti][tj] = __builtin_amdgcn_mfma_f32_16x16x32_bf16(qf[ti], kf[tj], S[ti][tj], 0, 0, 0);

  int catx[4], caty[4], catz[4];
  #pragma unroll
  for (int a = 0; a < 4; ++a) {
    catx[a] = (gx < 7) ? 0 : ((a < 2) ? 1 : 2);
    caty[a] = (gy < 7) ? 0 : ((a < 2) ? 1 : 2);
    catz[a] = (gz < 7) ? 0 : ((a < 2) ? 1 : 2);
  }
  const int cy = (m >> 2) & 3, cz = m & 3;
  int labc[4], labr[16];
  #pragma unroll
  for (int tj = 0; tj < 4; ++tj) labc[tj] = catx[tj] * 9 + caty[cy] * 3 + catz[cz];
  #pragma unroll
  for (int ti = 0; ti < 4; ++ti)
    #pragma unroll
    for (int r = 0; r < 4; ++r) labr[ti * 4 + r] = catx[ti] * 9 + caty[q4] * 3 + catz[r];

  #pragma unroll
  for (int ti = 0; ti < 4; ++ti)
    #pragma unroll
    for (int tj = 0; tj < 4; ++tj) {
      int K0 = 11 * (ti - tj + 3) + (q4 + 3 - cy) + (3 - cz);
      #pragma unroll
      for (int r = 0; r < 4; ++r) {
        float v = S[ti][tj][r] + bias_s[wv][K0 + r];
        if (labr[ti * 4 + r] != labc[tj]) v -= 100.f;
        S[ti][tj][r] = v;
      }
    }

  float mx[16], sm[16];
  #pragma unroll
  for (int ti = 0; ti < 4; ++ti)
    #pragma unroll
    for (int r = 0; r < 4; ++r)
      mx[ti * 4 + r] = fmaxf(fmaxf(S[ti][0][r], S[ti][1][r]), fmaxf(S[ti][2][r], S[ti][3][r]));
  #pragma unroll
  for (int off = 1; off < 16; off <<= 1)
    #pragma unroll
    for (int i = 0; i < 16; ++i) mx[i] = fmaxf(mx[i], __shfl_xor(mx[i], off, 64));
  #pragma unroll
  for (int ti = 0; ti < 4; ++ti)
    #pragma unroll
    for (int r = 0; r < 4; ++r) {
      float e0 = __expf(S[ti][0][r] - mx[ti * 4 + r]);
      float e1 = __expf(S[ti][1][r] - mx[ti * 4 + r]);
      float e2 = __expf(S[ti][2][r] - mx[ti * 4 + r]);
      float e3 = __expf(S[ti][3][r] - mx[ti * 4 + r]);
      S[ti][0][r] = e0; S[ti][1][r] = e1; S[ti][2][r] = e2; S[ti][3][r] = e3;
      sm[ti * 4 + r] = (e0 + e1) + (e2 + e3);
    }
  #pragma unroll
  for (int off = 1; off < 16; off <<= 1)
    #pragma unroll
    for (int i = 0; i < 16; ++i) sm[i] += __shfl_xor(sm[i], off, 64);
  #pragma unroll
  for (int i = 0; i < 16; ++i) sm[i] = 1.f / sm[i];

  #pragma unroll
  for (int ti = 0; ti < 4; ++ti)
    #pragma unroll
    for (int tj = 0; tj < 4; ++tj)
      #pragma unroll
      for (int r = 0; r < 4; ++r)
        P_s[wv][ti * 16 + q4 * 4 + r][tj * 16 + m] = f2bf(S[ti][tj][r]);

  f32x4 O[4][2];
  #pragma unroll
  for (int ti = 0; ti < 4; ++ti)
    #pragma unroll
    for (int tv = 0; tv < 2; ++tv) O[ti][tv] = zero;
  #pragma unroll
  for (int ks = 0; ks < 2; ++ks) {
    short8 pa[4], vb[2];
    #pragma unroll
    for (int ti = 0; ti < 4; ++ti)
      pa[ti] = *(const short8*)&P_s[wv][ti * 16 + m][ks * 32 + q4 * 8];
    #pragma unroll
    for (int tv = 0; tv < 2; ++tv)
      vb[tv] = *(const short8*)&Vt_s[wv][tv * 16 + m][ks * 32 + q4 * 8];
    #pragma unroll
    for (int ti = 0; ti < 4; ++ti)
      #pragma unroll
      for (int tv = 0; tv < 2; ++tv)
        O[ti][tv] = __builtin_amdgcn_mfma_f32_16x16x32_bf16(pa[ti], vb[tv], O[ti][tv], 0, 0, 0);
  }

  #pragma unroll
  for (int ti = 0; ti < 4; ++ti)
    #pragma unroll
    for (int tv = 0; tv < 2; ++tv)
      #pragma unroll
      for (int r = 0; r < 4; ++r) {
        int n = ti * 16 + q4 * 4 + r;
        att[(base + n) * 128 + wv * 32 + tv * 16 + m] = f2bf(O[ti][tv][r] * sm[ti * 4 + r]);
      }
}

// ---------------- proj GEMM + reverse-partition/unshift scatter + 0.5*out + inputs -> x (fp32) ----------------
__global__ __launch_bounds__(256) void k_proj(const u16* __restrict__ att,
                                              const u16* __restrict__ wT,
                                              const float* __restrict__ proj_b,
                                              const float* __restrict__ inputs,
                                              float* __restrict__ xws) {
  __shared__ __align__(16) u16 A_s[64 * 136];
  __shared__ __align__(16) u16 B_s[128 * 136];
  const int t = threadIdx.x, wid = t >> 6, lane = t & 63;
  const size_t mbase = (size_t)blockIdx.x * 64;
  {
    int r = t >> 2, seg = t & 3;
    const short8* src = (const short8*)(att + (mbase + r) * 128 + seg * 32);
    short8* dst = (short8*)(A_s + r * 136 + seg * 32);
    #pragma unroll
    for (int i = 0; i < 4; ++i) dst[i] = src[i];
  }
  {
    int r = t >> 1, half = t & 1;
    const short8* src = (const short8*)(wT + (size_t)r * 128 + half * 64);
    short8* dst = (short8*)(B_s + r * 136 + half * 64);
    #pragma unroll
    for (int i = 0; i < 8; ++i) dst[i] = src[i];
  }
  __syncthreads();
  f32x4 zero = {0.f, 0.f, 0.f, 0.f};
  f32x4 acc[2][4];
  #pragma unroll
  for (int tm = 0; tm < 2; ++tm)
    #pragma unroll
    for (int tn = 0; tn < 4; ++tn) acc[tm][tn] = zero;
  mfma_64x128(A_s, B_s, acc, wid, lane);
  const int m = lane & 15, kg = lane >> 4;
  const int ro = (wid & 1) * 32, co = (wid >> 1) * 64;
  #pragma unroll
  for (int tm = 0; tm < 2; ++tm)
    #pragma unroll
    for (int r = 0; r < 4; ++r) {
      int row = ro + tm * 16 + kg * 4 + r;
      size_t o = mbase + row;
      int nn = (int)(o & 63), wbox = (int)((o >> 6) & 511), bb = (int)(o >> 15);
      int gx = wbox >> 6, gy = (wbox >> 3) & 7, gz = wbox & 7;
      int ix = nn >> 4, iy = (nn >> 2) & 3, iz = nn & 3;
      int X = (gx * 4 + ix + 2) & 31, Y = (gy * 4 + iy + 2) & 31, Z = (gz * 4 + iz + 2) & 31;
      size_t orig = ((size_t)bb << 15) + (size_t)(X * 1024 + Y * 32 + Z);
      #pragma unroll
      for (int tn = 0; tn < 4; ++tn) {
        int col = co + tn * 16 + m;
        float v = acc[tm][tn][r] + proj_b[col];
        xws[orig * 128 + col] = 0.5f * v + inputs[orig * 128 + col];
      }
    }
}

// ---------------- fused LN2 + MLP: A-frags in regs, wave-private H, 3 blocks/CU ----------------
// R1 changes: (a) GELU erff -> branchless v*sigmoid(1.5958v+0.0714v^3) via v_exp/v_rcp
//             (b) T14 async-STAGE split: next nt's w1/w2 tiles prefetched into regs AFTER the
//                 second barrier (so no vmcnt(0) barrier-drain), LDS-written at next iter top.
__global__ __launch_bounds__(256) void k_mlp(const float* __restrict__ x,
                                             const u16* __restrict__ w1T,
                                             const u16* __restrict__ w2T,
                                             const float* __restrict__ g2,
                                             const float* __restrict__ b2,
                                             const float* __restrict__ bb1,
                                             const float* __restrict__ bb2,
                                             float* __restrict__ out) {
  // LDS layout (53248 B total -> 3 blocks/CU):
  //   [0,17408)      B1_s [64][136]  (w1 tile; pre-loop overlay: red[64][8] floats)
  //   [17408,35840)  B2_s [128][72]  (w2 tile)
  //   [35840,53248)  A_s  [64][136]  (LN2 out; reused as H [64][72] inside loop)
  __shared__ __align__(16) char lds[53248];
  u16* B1_s = (u16*)lds;
  u16* B2_s = (u16*)(lds + 17408);
  u16* A_s  = (u16*)(lds + 35840);
  u16* H_s  = (u16*)(lds + 35840);
  float* red = (float*)lds;

  const int t = threadIdx.x, wid = t >> 6, lane = t & 63;
  const int m = lane & 15, q4 = lane >> 4;
  const size_t mbase = (size_t)blockIdx.x * 64;

  const int r1 = t >> 2, seg = t & 3;    // B1 staging coords
  const int r2 = t >> 1, half = t & 1;   // B2 staging coords

  // ---- prefetch nt=0 weight tiles into regs (latency hidden under LN2) ----
  short8 b1r[4], b2r[4];
  {
    const short8* s1 = (const short8*)(w1T + (size_t)r1 * 128 + seg * 32);
    #pragma unroll
    for (int i = 0; i < 4; ++i) b1r[i] = s1[i];
    const short8* s2 = (const short8*)(w2T + (size_t)r2 * 512 + half * 32);
    #pragma unroll
    for (int i = 0; i < 4; ++i) b2r[i] = s2[i];
  }

  // ---- LN2: entirely wave-local (rows 16w..16w+15 handled by wave w) ----
  {
    const float4* x4 = (const float4*)(x + (mbase + r1) * 128 + seg * 32);
    float vals[32];
    float s = 0.f, ss = 0.f;
    #pragma unroll
    for (int i = 0; i < 8; ++i) {
      float4 v = x4[i];
      vals[4 * i] = v.x; vals[4 * i + 1] = v.y; vals[4 * i + 2] = v.z; vals[4 * i + 3] = v.w;
      s += v.x + v.y + v.z + v.w;
      ss += v.x * v.x + v.y * v.y + v.z * v.z + v.w * v.w;
    }
    red[r1 * 8 + seg] = s; red[r1 * 8 + 4 + seg] = ss;
    float sum = red[r1 * 8 + 0] + red[r1 * 8 + 1] + red[r1 * 8 + 2] + red[r1 * 8 + 3];
    float sq  = red[r1 * 8 + 4] + red[r1 * 8 + 5] + red[r1 * 8 + 6] + red[r1 * 8 + 7];
    float mean = sum * 0.0078125f;
    float var = sq * 0.0078125f - mean * mean;
    float rs = rsqrtf(var + 1e-5f);
    #pragma unroll
    for (int i = 0; i < 32; ++i) {
      int c = seg * 32 + i;
      A_s[r1 * 136 + c] = f2bf((vals[i] - mean) * rs * g2[c] + b2[c]);
    }
  }
  // ---- A fragments -> registers (wave-local rows; held for whole loop) ----
  short8 af[4];
  #pragma unroll
  for (int kc = 0; kc < 4; ++kc)
    af[kc] = *(const short8*)(A_s + (wid * 16 + m) * 136 + kc * 32 + q4 * 8);

  f32x4 zero = {0.f, 0.f, 0.f, 0.f};
  f32x4 acc[8];
  #pragma unroll
  for (int tn = 0; tn < 8; ++tn) acc[tn] = zero;

  for (int nt = 0; nt < 8; ++nt) {
    __syncthreads();   // prior-iter B reads (and pre-loop red/A-frag reads) done
    // ---- LDS-write this tile from prefetched regs ----
    {
      short8* dst = (short8*)(B1_s + r1 * 136 + seg * 32);
      #pragma unroll
      for (int i = 0; i < 4; ++i) dst[i] = b1r[i];
      short8* dst2 = (short8*)(B2_s + r2 * 72 + half * 32);
      #pragma unroll
      for (int i = 0; i < 4; ++i) dst2[i] = b2r[i];
    }
    __syncthreads();
    // ---- issue next tile's global loads NOW (no barrier until after compute) ----
    if (nt < 7) {
      const short8* s1 = (const short8*)(w1T + (size_t)((nt + 1) * 64 + r1) * 128 + seg * 32);
      #pragma unroll
      for (int i = 0; i < 4; ++i) b1r[i] = s1[i];
      const short8* s2 = (const short8*)(w2T + (size_t)r2 * 512 + (nt + 1) * 64 + half * 32);
      #pragma unroll
      for (int i = 0; i < 4; ++i) b2r[i] = s2[i];
    }
    // GEMM1: 16 rows x 64 cols per wave
    f32x4 hacc[4];
    #pragma unroll
    for (int tn = 0; tn < 4; ++tn) hacc[tn] = zero;
    #pragma unroll
    for (int kc = 0; kc < 4; ++kc) {
      short8 b[4];
      #pragma unroll
      for (int tn = 0; tn < 4; ++tn)
        b[tn] = *(const short8*)(B1_s + (tn * 16 + m) * 136 + kc * 32 + q4 * 8);
      #pragma unroll
      for (int tn = 0; tn < 4; ++tn)
        hacc[tn] = __builtin_amdgcn_mfma_f32_16x16x32_bf16(af[kc], b[tn], hacc[tn], 0, 0, 0);
    }
    // GELU (tanh-form, branchless) -> wave-private H rows (no barrier: producer == consumer)
    #pragma unroll
    for (int tn = 0; tn < 4; ++tn)
      #pragma unroll
      for (int r = 0; r < 4; ++r) {
        int rl = q4 * 4 + r;
        float v = hacc[tn][r] + bb1[nt * 64 + tn * 16 + m];
        // gelu(v) ~= v * sigmoid(1.5957691v + 0.07135482v^3); exact for this input range
        // (|v| <~ 1.4 => err < 3e-4, well under bf16 rounding of H)
        float v2 = v * v;
        float qe = v * __builtin_fmaf(-0.07135482f, v2, -1.5957691f);
        float te = __expf(qe);
        float gl = v * __builtin_amdgcn_rcpf(1.f + te);
        H_s[(wid * 16 + rl) * 72 + tn * 16 + m] = f2bf(gl);
      }
    // GEMM2: 16 rows x 128 cols per wave, accumulate
    #pragma unroll
    for (int kc2 = 0; kc2 < 2; ++kc2) {
      short8 pa = *(const short8*)(H_s + (wid * 16 + m) * 72 + kc2 * 32 + q4 * 8);
      #pragma unroll
      for (int tn = 0; tn < 8; ++tn) {
        short8 b = *(const short8*)(B2_s + (tn * 16 + m) * 72 + kc2 * 32 + q4 * 8);
        acc[tn] = __builtin_amdgcn_mfma_f32_16x16x32_bf16(pa, b, acc[tn], 0, 0, 0);
      }
    }
  }
  // epilogue: 0.5*mlp + x
  #pragma unroll
  for (int tn = 0; tn < 8; ++tn)
    #pragma unroll
    for (int r = 0; r < 4; ++r) {
      int row = wid * 16 + q4 * 4 + r;
      int col = tn * 16 + m;
      size_t tok = mbase + row;
      float v = acc[tn][r] + bb2[col];
      out[tok * 128 + col] = 0.5f * v + x[tok * 128 + col];
    }
}

extern "C" void kernel_launch(void* const* d_in, const int* in_sizes, int n_in,
                              void* d_out, int out_size, void* d_ws, size_t ws_size,
                              hipStream_t stream) {
  const float* inputs = (const float*)d_in[0];
  const float* qkv_w  = (const float*)d_in[1];
  const float* proj_w = (const float*)d_in[2];
  const float* proj_b = (const float*)d_in[3];
  const float* btab   = (const float*)d_in[4];
  const float* g1     = (const float*)d_in[5];
  const float* b1     = (const float*)d_in[6];
  const float* g2     = (const float*)d_in[7];
  const float* b2     = (const float*)d_in[8];
  const float* w1     = (const float*)d_in[9];
  const float* bb1    = (const float*)d_in[10];
  const float* w2     = (const float*)d_in[11];
  const float* bb2    = (const float*)d_in[12];
  float* out = (float*)d_out;

  char* ws = (char*)d_ws;
  u16* qkvT  = (u16*)(ws + 0);          // 384*128 bf16
  u16* projT = (u16*)(ws + 98304);      // 128*128
  u16* w1T   = (u16*)(ws + 131072);     // 512*128
  u16* w2T   = (u16*)(ws + 262144);     // 128*512
  u16* lnb   = (u16*)(ws + 393216);     // T*128 bf16 (reused as attn_out)
  u16* qkv   = (u16*)(ws + 393216 + 67108864);  // T*384 bf16 (reused as x fp32)
  u16* att   = lnb;                     // overlay: lnb dead after k_qkv
  float* xws = (float*)qkv;             // overlay: qkv dead after k_attn

  k_wprep<<<192, 256, 0, stream>>>(qkv_w, qkvT, 128, 384);
  k_wprep<<<64, 256, 0, stream>>>(proj_w, projT, 128, 128);
  k_wprep<<<256, 256, 0, stream>>>(w1, w1T, 128, 512);
  k_wprep<<<256, 256, 0, stream>>>(w2, w2T, 512, 128);

  k_ln1<<<65536, 256, 0, stream>>>(inputs, g1, b1, lnb);
  k_qkv<<<dim3(4096, 3), 256, 0, stream>>>(lnb, qkvT, qkv);
  k_attn<<<4096, 256, 0, stream>>>(qkv, btab, att);
  k_proj<<<4096, 256, 0, stream>>>(att, projT, proj_b, inputs, xws);
  k_mlp<<<4096, 256, 0, stream>>>(xws, w1T, w2T, g2, b2, bb1, bb2, out);
}

// Round 2
// 664.392 us; speedup vs baseline: 1.0208x; 1.0097x over previous
//
#include <hip/hip_runtime.h>
#include <hip/hip_bf16.h>

typedef unsigned short u16;
typedef unsigned int u32;
typedef __attribute__((ext_vector_type(8))) short short8;
typedef __attribute__((ext_vector_type(4))) float f32x4;

__device__ __forceinline__ u16 f2bf(float x) {
  __hip_bfloat16 h = __float2bfloat16(x);
  return *reinterpret_cast<u16*>(&h);
}
__device__ __forceinline__ float bflo(u32 u) { return __uint_as_float(u << 16); }
__device__ __forceinline__ float bfhi(u32 u) { return __uint_as_float(u & 0xffff0000u); }

// ---------------- weight transpose + cast: dst[n*K+k] = bf16(src[k*N+n]) ----------------
__global__ void k_wprep(const float* __restrict__ src, u16* __restrict__ dst, int K, int N) {
  int idx = blockIdx.x * 256 + threadIdx.x;
  if (idx >= K * N) return;
  int k = idx / N, n = idx - k * N;
  dst[n * K + k] = f2bf(src[idx]);
}

// ---------------- LN1 + roll(-2) + window partition -> bf16 [262144][128] ----------------
__global__ __launch_bounds__(256) void k_ln1(const float* __restrict__ in,
                                             const float* __restrict__ g1,
                                             const float* __restrict__ b1,
                                             u16* __restrict__ lnb) {
  int lane = threadIdx.x & 63;
  size_t o = (size_t)blockIdx.x * 4 + (threadIdx.x >> 6);
  int n = (int)(o & 63), wbox = (int)((o >> 6) & 511), b = (int)(o >> 15);
  int gx = wbox >> 6, gy = (wbox >> 3) & 7, gz = wbox & 7;
  int ix = n >> 4, iy = (n >> 2) & 3, iz = n & 3;
  int X = (gx * 4 + ix + 2) & 31, Y = (gy * 4 + iy + 2) & 31, Z = (gz * 4 + iz + 2) & 31;
  const float* row = in + (((size_t)b << 15) + (size_t)(X * 1024 + Y * 32 + Z)) * 128;
  float x0 = row[lane], x1 = row[lane + 64];
  float s = x0 + x1, ss = x0 * x0 + x1 * x1;
  #pragma unroll
  for (int off = 32; off > 0; off >>= 1) {
    s += __shfl_xor(s, off, 64);
    ss += __shfl_xor(ss, off, 64);
  }
  float mean = s * 0.0078125f;
  float var = ss * 0.0078125f - mean * mean;
  float rs = rsqrtf(var + 1e-5f);
  lnb[o * 128 + lane]      = f2bf((x0 - mean) * rs * g1[lane] + b1[lane]);
  lnb[o * 128 + lane + 64] = f2bf((x1 - mean) * rs * g1[lane + 64] + b1[lane + 64]);
}

// ---------------- shared 64x128-tile MFMA core: A_s [64][136], B_s(=W^T) [128][136] ----------------
__device__ __forceinline__ void mfma_64x128(const u16* A_s, const u16* B_s,
                                            f32x4 acc[2][4], int wid, int lane) {
  const int m = lane & 15, kg = lane >> 4;
  const int ro = (wid & 1) * 32, co = (wid >> 1) * 64;
  #pragma unroll
  for (int kc = 0; kc < 4; ++kc) {
    short8 a[2], b[4];
    #pragma unroll
    for (int tm = 0; tm < 2; ++tm)
      a[tm] = *(const short8*)(A_s + (ro + tm * 16 + m) * 136 + kc * 32 + kg * 8);
    #pragma unroll
    for (int tn = 0; tn < 4; ++tn)
      b[tn] = *(const short8*)(B_s + (co + tn * 16 + m) * 136 + kc * 32 + kg * 8);
    #pragma unroll
    for (int tm = 0; tm < 2; ++tm)
      #pragma unroll
      for (int tn = 0; tn < 4; ++tn)
        acc[tm][tn] = __builtin_amdgcn_mfma_f32_16x16x32_bf16(a[tm], b[tn], acc[tm][tn], 0, 0, 0);
  }
}

// ---------------- QKV GEMM: [T,128] x [128,384] -> bf16 qkv [T][384], q pre-scaled ----------------
__global__ __launch_bounds__(256) void k_qkv(const u16* __restrict__ lnb,
                                             const u16* __restrict__ wT,
                                             u16* __restrict__ qkv) {
  __shared__ __align__(16) u16 A_s[64 * 136];
  __shared__ __align__(16) u16 B_s[128 * 136];
  const int t = threadIdx.x, wid = t >> 6, lane = t & 63;
  const size_t mbase = (size_t)blockIdx.x * 64;
  const int n0 = blockIdx.y * 128;
  {
    int r = t >> 2, seg = t & 3;
    const short8* src = (const short8*)(lnb + (mbase + r) * 128 + seg * 32);
    short8* dst = (short8*)(A_s + r * 136 + seg * 32);
    #pragma unroll
    for (int i = 0; i < 4; ++i) dst[i] = src[i];
  }
  {
    int r = t >> 1, half = t & 1;
    const short8* src = (const short8*)(wT + (size_t)(n0 + r) * 128 + half * 64);
    short8* dst = (short8*)(B_s + r * 136 + half * 64);
    #pragma unroll
    for (int i = 0; i < 8; ++i) dst[i] = src[i];
  }
  __syncthreads();
  f32x4 zero = {0.f, 0.f, 0.f, 0.f};
  f32x4 acc[2][4];
  #pragma unroll
  for (int tm = 0; tm < 2; ++tm)
    #pragma unroll
    for (int tn = 0; tn < 4; ++tn) acc[tm][tn] = zero;
  mfma_64x128(A_s, B_s, acc, wid, lane);
  const int m = lane & 15, kg = lane >> 4;
  const int ro = (wid & 1) * 32, co = (wid >> 1) * 64;
  #pragma unroll
  for (int tm = 0; tm < 2; ++tm)
    #pragma unroll
    for (int tn = 0; tn < 4; ++tn)
      #pragma unroll
      for (int r = 0; r < 4; ++r) {
        int row = ro + tm * 16 + kg * 4 + r;
        int cc = n0 + co + tn * 16 + m;
        float v = acc[tm][tn][r];
        if (cc < 128) v *= 0.17677669529663687f;   // q * HD^-0.5
        qkv[(mbase + row) * 384 + cc] = f2bf(v);
      }
}

// ---------------- per-window attention, MFMA version: block=window, wave=head ----------------
__global__ __launch_bounds__(256) void k_attn(const u16* __restrict__ qkv,
                                              const float* __restrict__ btab,
                                              u16* __restrict__ att) {
  __shared__ float bias_s[4][128];               // [h][121] transposed bias table
  __shared__ __align__(16) u16 Vt_s[4][32][72];  // V^T per head: [d][key]
  __shared__ __align__(16) u16 P_s[4][64][72];   // exp(S-m) per head, unnormalized
  const int t = threadIdx.x;
  const int wv = t >> 6, lane = t & 63;
  const int m = lane & 15, q4 = lane >> 4;
  const int bw = blockIdx.x;
  const size_t base = (size_t)bw * 64;
  const int wbox = bw & 511;
  const int gx = wbox >> 6, gy = (wbox >> 3) & 7, gz = wbox & 7;

  for (int i = t; i < 484; i += 256) bias_s[i & 3][i >> 2] = btab[i];
  #pragma unroll
  for (int i = 0; i < 16; ++i) {
    int nn = i * 4 + wv;
    int ch = lane * 2;
    int hh = ch >> 5, d = ch & 31;
    u32 vv = *(const u32*)(qkv + (base + nn) * 384 + 256 + ch);
    Vt_s[hh][d][nn]     = (u16)(vv & 0xffffu);
    Vt_s[hh][d + 1][nn] = (u16)(vv >> 16);
  }

  short8 qf[4], kf[4];
  #pragma unroll
  for (int ti = 0; ti < 4; ++ti) {
    qf[ti] = *(const short8*)(qkv + (base + ti * 16 + m) * 384 + wv * 32 + q4 * 8);
    kf[ti] = *(const short8*)(qkv + (base + ti * 16 + m) * 384 + 128 + wv * 32 + q4 * 8);
  }

  f32x4 zero = {0.f, 0.f, 0.f, 0.f};
  f32x4 S[4][4];
  #pragma unroll
  for (int ti = 0; ti < 4; ++ti)
    #pragma unroll
    for (int tj = 0; tj < 4; ++tj) S[ti][tj] = zero;

  __syncthreads();

  #pragma unroll
  for (int ti = 0; ti < 4; ++ti)
    #pragma unroll
    for (int tj = 0; tj < 4; ++tj)
      S[ti][tj] = __builtin_amdgcn_mfma_f32_16x16x32_bf16(qf[ti], kf[tj], S[ti][tj], 0, 0, 0);

  int catx[4], caty[4], catz[4];
  #pragma unroll
  for (int a = 0; a < 4; ++a) {
    catx[a] = (gx < 7) ? 0 : ((a < 2) ? 1 : 2);
    caty[a] = (gy < 7) ? 0 : ((a < 2) ? 1 : 2);
    catz[a] = (gz < 7) ? 0 : ((a < 2) ? 1 : 2);
  }
  const int cy = (m >> 2) & 3, cz = m & 3;
  int labc[4], labr[16];
  #pragma unroll
  for (int tj = 0; tj < 4; ++tj) labc[tj] = catx[tj] * 9 + caty[cy] * 3 + catz[cz];
  #pragma unroll
  for (int ti = 0; ti < 4; ++ti)
    #pragma unroll
    for (int r = 0; r < 4; ++r) labr[ti * 4 + r] = catx[ti] * 9 + caty[q4] * 3 + catz[r];

  #pragma unroll
  for (int ti = 0; ti < 4; ++ti)
    #pragma unroll
    for (int tj = 0; tj < 4; ++tj) {
      int K0 = 11 * (ti - tj + 3) + (q4 + 3 - cy) + (3 - cz);
      #pragma unroll
      for (int r = 0; r < 4; ++r) {
        float v = S[ti][tj][r] + bias_s[wv][K0 + r];
        if (labr[ti * 4 + r] != labc[tj]) v -= 100.f;
        S[ti][tj][r] = v;
      }
    }

  float mx[16], sm[16];
  #pragma unroll
  for (int ti = 0; ti < 4; ++ti)
    #pragma unroll
    for (int r = 0; r < 4; ++r)
      mx[ti * 4 + r] = fmaxf(fmaxf(S[ti][0][r], S[ti][1][r]), fmaxf(S[ti][2][r], S[ti][3][r]));
  #pragma unroll
  for (int off = 1; off < 16; off <<= 1)
    #pragma unroll
    for (int i = 0; i < 16; ++i) mx[i] = fmaxf(mx[i], __shfl_xor(mx[i], off, 64));
  #pragma unroll
  for (int ti = 0; ti < 4; ++ti)
    #pragma unroll
    for (int r = 0; r < 4; ++r) {
      float e0 = __expf(S[ti][0][r] - mx[ti * 4 + r]);
      float e1 = __expf(S[ti][1][r] - mx[ti * 4 + r]);
      float e2 = __expf(S[ti][2][r] - mx[ti * 4 + r]);
      float e3 = __expf(S[ti][3][r] - mx[ti * 4 + r]);
      S[ti][0][r] = e0; S[ti][1][r] = e1; S[ti][2][r] = e2; S[ti][3][r] = e3;
      sm[ti * 4 + r] = (e0 + e1) + (e2 + e3);
    }
  #pragma unroll
  for (int off = 1; off < 16; off <<= 1)
    #pragma unroll
    for (int i = 0; i < 16; ++i) sm[i] += __shfl_xor(sm[i], off, 64);
  #pragma unroll
  for (int i = 0; i < 16; ++i) sm[i] = 1.f / sm[i];

  #pragma unroll
  for (int ti = 0; ti < 4; ++ti)
    #pragma unroll
    for (int tj = 0; tj < 4; ++tj)
      #pragma unroll
      for (int r = 0; r < 4; ++r)
        P_s[wv][ti * 16 + q4 * 4 + r][tj * 16 + m] = f2bf(S[ti][tj][r]);

  f32x4 O[4][2];
  #pragma unroll
  for (int ti = 0; ti < 4; ++ti)
    #pragma unroll
    for (int tv = 0; tv < 2; ++tv) O[ti][tv] = zero;
  #pragma unroll
  for (int ks = 0; ks < 2; ++ks) {
    short8 pa[4], vb[2];
    #pragma unroll
    for (int ti = 0; ti < 4; ++ti)
      pa[ti] = *(const short8*)&P_s[wv][ti * 16 + m][ks * 32 + q4 * 8];
    #pragma unroll
    for (int tv = 0; tv < 2; ++tv)
      vb[tv] = *(const short8*)&Vt_s[wv][tv * 16 + m][ks * 32 + q4 * 8];
    #pragma unroll
    for (int ti = 0; ti < 4; ++ti)
      #pragma unroll
      for (int tv = 0; tv < 2; ++tv)
        O[ti][tv] = __builtin_amdgcn_mfma_f32_16x16x32_bf16(pa[ti], vb[tv], O[ti][tv], 0, 0, 0);
  }

  #pragma unroll
  for (int ti = 0; ti < 4; ++ti)
    #pragma unroll
    for (int tv = 0; tv < 2; ++tv)
      #pragma unroll
      for (int r = 0; r < 4; ++r) {
        int n = ti * 16 + q4 * 4 + r;
        att[(base + n) * 128 + wv * 32 + tv * 16 + m] = f2bf(O[ti][tv][r] * sm[ti * 4 + r]);
      }
}

// ---------------- proj GEMM + reverse-partition/unshift scatter + 0.5*out + inputs -> x (fp32) ----------------
__global__ __launch_bounds__(256) void k_proj(const u16* __restrict__ att,
                                              const u16* __restrict__ wT,
                                              const float* __restrict__ proj_b,
                                              const float* __restrict__ inputs,
                                              float* __restrict__ xws) {
  __shared__ __align__(16) u16 A_s[64 * 136];
  __shared__ __align__(16) u16 B_s[128 * 136];
  const int t = threadIdx.x, wid = t >> 6, lane = t & 63;
  const size_t mbase = (size_t)blockIdx.x * 64;
  {
    int r = t >> 2, seg = t & 3;
    const short8* src = (const short8*)(att + (mbase + r) * 128 + seg * 32);
    short8* dst = (short8*)(A_s + r * 136 + seg * 32);
    #pragma unroll
    for (int i = 0; i < 4; ++i) dst[i] = src[i];
  }
  {
    int r = t >> 1, half = t & 1;
    const short8* src = (const short8*)(wT + (size_t)r * 128 + half * 64);
    short8* dst = (short8*)(B_s + r * 136 + half * 64);
    #pragma unroll
    for (int i = 0; i < 8; ++i) dst[i] = src[i];
  }
  __syncthreads();
  f32x4 zero = {0.f, 0.f, 0.f, 0.f};
  f32x4 acc[2][4];
  #pragma unroll
  for (int tm = 0; tm < 2; ++tm)
    #pragma unroll
    for (int tn = 0; tn < 4; ++tn) acc[tm][tn] = zero;
  mfma_64x128(A_s, B_s, acc, wid, lane);
  const int m = lane & 15, kg = lane >> 4;
  const int ro = (wid & 1) * 32, co = (wid >> 1) * 64;
  #pragma unroll
  for (int tm = 0; tm < 2; ++tm)
    #pragma unroll
    for (int r = 0; r < 4; ++r) {
      int row = ro + tm * 16 + kg * 4 + r;
      size_t o = mbase + row;
      int nn = (int)(o & 63), wbox = (int)((o >> 6) & 511), bb = (int)(o >> 15);
      int gx = wbox >> 6, gy = (wbox >> 3) & 7, gz = wbox & 7;
      int ix = nn >> 4, iy = (nn >> 2) & 3, iz = nn & 3;
      int X = (gx * 4 + ix + 2) & 31, Y = (gy * 4 + iy + 2) & 31, Z = (gz * 4 + iz + 2) & 31;
      size_t orig = ((size_t)bb << 15) + (size_t)(X * 1024 + Y * 32 + Z);
      #pragma unroll
      for (int tn = 0; tn < 4; ++tn) {
        int col = co + tn * 16 + m;
        float v = acc[tm][tn][r] + proj_b[col];
        xws[orig * 128 + col] = 0.5f * v + inputs[orig * 128 + col];
      }
    }
}

// ---------------- fused LN2 + MLP, R2 restructure: N-split waves, weights direct from L2 ----------------
// Theory: R1 counters showed no pipe >40% -> barrier/LDS-serialization bound. This version:
//   * GEMM1 N-split: wave w computes H[64][16w..16w+15]; reads ONLY its W1 slice direct from
//     global (L2-hot, 256KB total weights) -> zero LDS staging, zero cross-wave redundancy.
//   * GEMM2 N-split: wave w computes out[64][32w..32w+31]; reads ONLY its W2 slice direct.
//   * A (LN2 out) read once into regs (16 short8), held whole loop.
//   * Only H goes through LDS (8KB/iter, double-buffered) -> ONE barrier per iter (was 2).
//   * T14: B2 loads issued after GEMM1 (hide under GELU+barrier); next B1 after barrier
//     (hide under GEMM2).
// LDS: A_s 17408 + H 2x9216 = 35840 B.
__global__ __launch_bounds__(256) void k_mlp(const float* __restrict__ x,
                                             const u16* __restrict__ w1T,
                                             const u16* __restrict__ w2T,
                                             const float* __restrict__ g2,
                                             const float* __restrict__ b2,
                                             const float* __restrict__ bb1,
                                             const float* __restrict__ bb2,
                                             float* __restrict__ out) {
  __shared__ __align__(16) char lds[35840];
  u16* A_s = (u16*)lds;                       // [64][136] LN2 output (bf16)
  u16* H0  = (u16*)(lds + 17408);             // [64][72] H buffer 0
  u16* H1  = (u16*)(lds + 17408 + 9216);      // [64][72] H buffer 1
  float* red = (float*)(lds + 17408);         // pre-loop overlay on H0 (LN2 partials)

  const int t = threadIdx.x, wid = t >> 6, lane = t & 63;
  const int m = lane & 15, q4 = lane >> 4;
  const size_t mbase = (size_t)blockIdx.x * 64;

  // ---- prefetch nt=0 W1 slice (latency hidden under LN2) ----
  short8 b1p[4];
  #pragma unroll
  for (int kc = 0; kc < 4; ++kc)
    b1p[kc] = *(const short8*)(w1T + (size_t)(wid * 16 + m) * 128 + kc * 32 + q4 * 8);

  // ---- LN2 (same as before; red overlays H0, dead before first H write) ----
  {
    int r1 = t >> 2, seg = t & 3;
    const float4* x4 = (const float4*)(x + (mbase + r1) * 128 + seg * 32);
    float vals[32];
    float s = 0.f, ss = 0.f;
    #pragma unroll
    for (int i = 0; i < 8; ++i) {
      float4 v = x4[i];
      vals[4 * i] = v.x; vals[4 * i + 1] = v.y; vals[4 * i + 2] = v.z; vals[4 * i + 3] = v.w;
      s += v.x + v.y + v.z + v.w;
      ss += v.x * v.x + v.y * v.y + v.z * v.z + v.w * v.w;
    }
    red[r1 * 8 + seg] = s; red[r1 * 8 + 4 + seg] = ss;
    float sum = red[r1 * 8 + 0] + red[r1 * 8 + 1] + red[r1 * 8 + 2] + red[r1 * 8 + 3];
    float sq  = red[r1 * 8 + 4] + red[r1 * 8 + 5] + red[r1 * 8 + 6] + red[r1 * 8 + 7];
    float mean = sum * 0.0078125f;
    float var = sq * 0.0078125f - mean * mean;
    float rs = rsqrtf(var + 1e-5f);
    #pragma unroll
    for (int i = 0; i < 32; ++i) {
      int c = seg * 32 + i;
      A_s[r1 * 136 + c] = f2bf((vals[i] - mean) * rs * g2[c] + b2[c]);
    }
  }
  __syncthreads();   // A_s complete (also: red reads done before H0 first written)

  // ---- ALL 64 rows of A -> registers, held for the whole loop ----
  short8 af[4][4];   // [kc][mt]
  #pragma unroll
  for (int kc = 0; kc < 4; ++kc)
    #pragma unroll
    for (int mt = 0; mt < 4; ++mt)
      af[kc][mt] = *(const short8*)(A_s + (mt * 16 + m) * 136 + kc * 32 + q4 * 8);

  f32x4 zero = {0.f, 0.f, 0.f, 0.f};
  f32x4 acc[4][2];   // [mt][nt2]: out rows 16mt+4q4+r, cols 32*wid+16*nt2+m
  #pragma unroll
  for (int mt = 0; mt < 4; ++mt)
    #pragma unroll
    for (int nt2 = 0; nt2 < 2; ++nt2) acc[mt][nt2] = zero;

  #pragma unroll
  for (int nt = 0; nt < 8; ++nt) {
    u16* Hb = (nt & 1) ? H1 : H0;
    // ---- GEMM1: H[64 rows][cols 16*wid..+16] = A @ W1-slice ----
    f32x4 hacc[4];
    #pragma unroll
    for (int mt = 0; mt < 4; ++mt) hacc[mt] = zero;
    #pragma unroll
    for (int kc = 0; kc < 4; ++kc)
      #pragma unroll
      for (int mt = 0; mt < 4; ++mt)
        hacc[mt] = __builtin_amdgcn_mfma_f32_16x16x32_bf16(af[kc][mt], b1p[kc], hacc[mt], 0, 0, 0);

    // ---- issue this iter's W2 slice now (hides under GELU + barrier) ----
    short8 b2f[2][2];  // [kc2][nt2]
    #pragma unroll
    for (int kc2 = 0; kc2 < 2; ++kc2)
      #pragma unroll
      for (int nt2 = 0; nt2 < 2; ++nt2)
        b2f[kc2][nt2] = *(const short8*)(w2T + (size_t)(wid * 32 + nt2 * 16 + m) * 512 +
                                         nt * 64 + kc2 * 32 + q4 * 8);

    // ---- GELU + bias -> H (wave's 16 cols) ----
    float bias1 = bb1[nt * 64 + wid * 16 + m];
    #pragma unroll
    for (int mt = 0; mt < 4; ++mt)
      #pragma unroll
      for (int r = 0; r < 4; ++r) {
        float v = hacc[mt][r] + bias1;
        float v2 = v * v;
        float qe = v * __builtin_fmaf(-0.07135482f, v2, -1.5957691f);
        float te = __expf(qe);
        float gl = v * __builtin_amdgcn_rcpf(1.f + te);
        Hb[(mt * 16 + q4 * 4 + r) * 72 + wid * 16 + m] = f2bf(gl);
      }
    __syncthreads();   // H tile complete (single barrier per iter; H double-buffered)

    // ---- prefetch next iter's W1 slice (hides under GEMM2) ----
    if (nt < 7) {
      #pragma unroll
      for (int kc = 0; kc < 4; ++kc)
        b1p[kc] = *(const short8*)(w1T + (size_t)((nt + 1) * 64 + wid * 16 + m) * 128 +
                                   kc * 32 + q4 * 8);
    }

    // ---- GEMM2: out[64 rows][cols 32*wid..+32] += H @ W2-slice ----
    #pragma unroll
    for (int kc2 = 0; kc2 < 2; ++kc2) {
      short8 a2[4];
      #pragma unroll
      for (int mt = 0; mt < 4; ++mt)
        a2[mt] = *(const short8*)(Hb + (mt * 16 + m) * 72 + kc2 * 32 + q4 * 8);
      #pragma unroll
      for (int mt = 0; mt < 4; ++mt)
        #pragma unroll
        for (int nt2 = 0; nt2 < 2; ++nt2)
          acc[mt][nt2] = __builtin_amdgcn_mfma_f32_16x16x32_bf16(a2[mt], b2f[kc2][nt2],
                                                                 acc[mt][nt2], 0, 0, 0);
    }
  }

  // ---- epilogue: 0.5*mlp + x ----
  #pragma unroll
  for (int mt = 0; mt < 4; ++mt)
    #pragma unroll
    for (int nt2 = 0; nt2 < 2; ++nt2)
      #pragma unroll
      for (int r = 0; r < 4; ++r) {
        size_t tok = mbase + mt * 16 + q4 * 4 + r;
        int col = wid * 32 + nt2 * 16 + m;
        float v = acc[mt][nt2][r] + bb2[col];
        out[tok * 128 + col] = 0.5f * v + x[tok * 128 + col];
      }
}

extern "C" void kernel_launch(void* const* d_in, const int* in_sizes, int n_in,
                              void* d_out, int out_size, void* d_ws, size_t ws_size,
                              hipStream_t stream) {
  const float* inputs = (const float*)d_in[0];
  const float* qkv_w  = (const float*)d_in[1];
  const float* proj_w = (const float*)d_in[2];
  const float* proj_b = (const float*)d_in[3];
  const float* btab   = (const float*)d_in[4];
  const float* g1     = (const float*)d_in[5];
  const float* b1     = (const float*)d_in[6];
  const float* g2     = (const float*)d_in[7];
  const float* b2     = (const float*)d_in[8];
  const float* w1     = (const float*)d_in[9];
  const float* bb1    = (const float*)d_in[10];
  const float* w2     = (const float*)d_in[11];
  const float* bb2    = (const float*)d_in[12];
  float* out = (float*)d_out;

  char* ws = (char*)d_ws;
  u16* qkvT  = (u16*)(ws + 0);          // 384*128 bf16
  u16* projT = (u16*)(ws + 98304);      // 128*128
  u16* w1T   = (u16*)(ws + 131072);     // 512*128
  u16* w2T   = (u16*)(ws + 262144);     // 128*512
  u16* lnb   = (u16*)(ws + 393216);     // T*128 bf16 (reused as attn_out)
  u16* qkv   = (u16*)(ws + 393216 + 67108864);  // T*384 bf16 (reused as x fp32)
  u16* att   = lnb;                     // overlay: lnb dead after k_qkv
  float* xws = (float*)qkv;             // overlay: qkv dead after k_attn

  k_wprep<<<192, 256, 0, stream>>>(qkv_w, qkvT, 128, 384);
  k_wprep<<<64, 256, 0, stream>>>(proj_w, projT, 128, 128);
  k_wprep<<<256, 256, 0, stream>>>(w1, w1T, 128, 512);
  k_wprep<<<256, 256, 0, stream>>>(w2, w2T, 512, 128);

  k_ln1<<<65536, 256, 0, stream>>>(inputs, g1, b1, lnb);
  k_qkv<<<dim3(4096, 3), 256, 0, stream>>>(lnb, qkvT, qkv);
  k_attn<<<4096, 256, 0, stream>>>(qkv, btab, att);
  k_proj<<<4096, 256, 0, stream>>>(att, projT, proj_b, inputs, xws);
  k_mlp<<<4096, 256, 0, stream>>>(xws, w1T, w2T, g2, b2, bb1, bb2, out);
}

// Round 3
// 660.130 us; speedup vs baseline: 1.0274x; 1.0065x over previous
//
#include <hip/hip_runtime.h>
#include <hip/hip_bf16.h>

typedef unsigned short u16;
typedef unsigned int u32;
typedef __attribute__((ext_vector_type(8))) short short8;
typedef __attribute__((ext_vector_type(4))) float f32x4;

__device__ __forceinline__ u16 f2bf(float x) {
  __hip_bfloat16 h = __float2bfloat16(x);
  return *reinterpret_cast<u16*>(&h);
}
__device__ __forceinline__ float bflo(u32 u) { return __uint_as_float(u << 16); }
__device__ __forceinline__ float bfhi(u32 u) { return __uint_as_float(u & 0xffff0000u); }

// ---------------- weight transpose + cast: dst[n*K+k] = bf16(src[k*N+n]) ----------------
__global__ void k_wprep(const float* __restrict__ src, u16* __restrict__ dst, int K, int N) {
  int idx = blockIdx.x * 256 + threadIdx.x;
  if (idx >= K * N) return;
  int k = idx / N, n = idx - k * N;
  dst[n * K + k] = f2bf(src[idx]);
}

// ---------------- LN1 + roll(-2) + window partition -> bf16 [262144][128] ----------------
__global__ __launch_bounds__(256) void k_ln1(const float* __restrict__ in,
                                             const float* __restrict__ g1,
                                             const float* __restrict__ b1,
                                             u16* __restrict__ lnb) {
  int lane = threadIdx.x & 63;
  size_t o = (size_t)blockIdx.x * 4 + (threadIdx.x >> 6);
  int n = (int)(o & 63), wbox = (int)((o >> 6) & 511), b = (int)(o >> 15);
  int gx = wbox >> 6, gy = (wbox >> 3) & 7, gz = wbox & 7;
  int ix = n >> 4, iy = (n >> 2) & 3, iz = n & 3;
  int X = (gx * 4 + ix + 2) & 31, Y = (gy * 4 + iy + 2) & 31, Z = (gz * 4 + iz + 2) & 31;
  const float* row = in + (((size_t)b << 15) + (size_t)(X * 1024 + Y * 32 + Z)) * 128;
  float x0 = row[lane], x1 = row[lane + 64];
  float s = x0 + x1, ss = x0 * x0 + x1 * x1;
  #pragma unroll
  for (int off = 32; off > 0; off >>= 1) {
    s += __shfl_xor(s, off, 64);
    ss += __shfl_xor(ss, off, 64);
  }
  float mean = s * 0.0078125f;
  float var = ss * 0.0078125f - mean * mean;
  float rs = rsqrtf(var + 1e-5f);
  lnb[o * 128 + lane]      = f2bf((x0 - mean) * rs * g1[lane] + b1[lane]);
  lnb[o * 128 + lane + 64] = f2bf((x1 - mean) * rs * g1[lane + 64] + b1[lane + 64]);
}

// ---------------- shared 64x128-tile MFMA core: A_s [64][136], B_s(=W^T) [128][136] ----------------
__device__ __forceinline__ void mfma_64x128(const u16* A_s, const u16* B_s,
                                            f32x4 acc[2][4], int wid, int lane) {
  const int m = lane & 15, kg = lane >> 4;
  const int ro = (wid & 1) * 32, co = (wid >> 1) * 64;
  #pragma unroll
  for (int kc = 0; kc < 4; ++kc) {
    short8 a[2], b[4];
    #pragma unroll
    for (int tm = 0; tm < 2; ++tm)
      a[tm] = *(const short8*)(A_s + (ro + tm * 16 + m) * 136 + kc * 32 + kg * 8);
    #pragma unroll
    for (int tn = 0; tn < 4; ++tn)
      b[tn] = *(const short8*)(B_s + (co + tn * 16 + m) * 136 + kc * 32 + kg * 8);
    #pragma unroll
    for (int tm = 0; tm < 2; ++tm)
      #pragma unroll
      for (int tn = 0; tn < 4; ++tn)
        acc[tm][tn] = __builtin_amdgcn_mfma_f32_16x16x32_bf16(a[tm], b[tn], acc[tm][tn], 0, 0, 0);
  }
}

// ---------------- QKV GEMM: [T,128] x [128,384] -> bf16 qkv [T][384], q pre-scaled ----------------
__global__ __launch_bounds__(256) void k_qkv(const u16* __restrict__ lnb,
                                             const u16* __restrict__ wT,
                                             u16* __restrict__ qkv) {
  __shared__ __align__(16) u16 A_s[64 * 136];
  __shared__ __align__(16) u16 B_s[128 * 136];
  const int t = threadIdx.x, wid = t >> 6, lane = t & 63;
  const size_t mbase = (size_t)blockIdx.x * 64;
  const int n0 = blockIdx.y * 128;
  {
    int r = t >> 2, seg = t & 3;
    const short8* src = (const short8*)(lnb + (mbase + r) * 128 + seg * 32);
    short8* dst = (short8*)(A_s + r * 136 + seg * 32);
    #pragma unroll
    for (int i = 0; i < 4; ++i) dst[i] = src[i];
  }
  {
    int r = t >> 1, half = t & 1;
    const short8* src = (const short8*)(wT + (size_t)(n0 + r) * 128 + half * 64);
    short8* dst = (short8*)(B_s + r * 136 + half * 64);
    #pragma unroll
    for (int i = 0; i < 8; ++i) dst[i] = src[i];
  }
  __syncthreads();
  f32x4 zero = {0.f, 0.f, 0.f, 0.f};
  f32x4 acc[2][4];
  #pragma unroll
  for (int tm = 0; tm < 2; ++tm)
    #pragma unroll
    for (int tn = 0; tn < 4; ++tn) acc[tm][tn] = zero;
  mfma_64x128(A_s, B_s, acc, wid, lane);
  const int m = lane & 15, kg = lane >> 4;
  const int ro = (wid & 1) * 32, co = (wid >> 1) * 64;
  #pragma unroll
  for (int tm = 0; tm < 2; ++tm)
    #pragma unroll
    for (int tn = 0; tn < 4; ++tn)
      #pragma unroll
      for (int r = 0; r < 4; ++r) {
        int row = ro + tm * 16 + kg * 4 + r;
        int cc = n0 + co + tn * 16 + m;
        float v = acc[tm][tn][r];
        if (cc < 128) v *= 0.17677669529663687f;   // q * HD^-0.5
        qkv[(mbase + row) * 384 + cc] = f2bf(v);
      }
}

// ---------------- per-window attention, MFMA version: block=window, wave=head ----------------
__global__ __launch_bounds__(256) void k_attn(const u16* __restrict__ qkv,
                                              const float* __restrict__ btab,
                                              u16* __restrict__ att) {
  __shared__ float bias_s[4][128];               // [h][121] transposed bias table
  __shared__ __align__(16) u16 Vt_s[4][32][72];  // V^T per head: [d][key]
  __shared__ __align__(16) u16 P_s[4][64][72];   // exp(S-m) per head, unnormalized
  const int t = threadIdx.x;
  const int wv = t >> 6, lane = t & 63;
  const int m = lane & 15, q4 = lane >> 4;
  const int bw = blockIdx.x;
  const size_t base = (size_t)bw * 64;
  const int wbox = bw & 511;
  const int gx = wbox >> 6, gy = (wbox >> 3) & 7, gz = wbox & 7;

  for (int i = t; i < 484; i += 256) bias_s[i & 3][i >> 2] = btab[i];
  #pragma unroll
  for (int i = 0; i < 16; ++i) {
    int nn = i * 4 + wv;
    int ch = lane * 2;
    int hh = ch >> 5, d = ch & 31;
    u32 vv = *(const u32*)(qkv + (base + nn) * 384 + 256 + ch);
    Vt_s[hh][d][nn]     = (u16)(vv & 0xffffu);
    Vt_s[hh][d + 1][nn] = (u16)(vv >> 16);
  }

  short8 qf[4], kf[4];
  #pragma unroll
  for (int ti = 0; ti < 4; ++ti) {
    qf[ti] = *(const short8*)(qkv + (base + ti * 16 + m) * 384 + wv * 32 + q4 * 8);
    kf[ti] = *(const short8*)(qkv + (base + ti * 16 + m) * 384 + 128 + wv * 32 + q4 * 8);
  }

  f32x4 zero = {0.f, 0.f, 0.f, 0.f};
  f32x4 S[4][4];
  #pragma unroll
  for (int ti = 0; ti < 4; ++ti)
    #pragma unroll
    for (int tj = 0; tj < 4; ++tj) S[ti][tj] = zero;

  __syncthreads();

  #pragma unroll
  for (int ti = 0; ti < 4; ++ti)
    #pragma unroll
    for (int tj = 0; tj < 4; ++tj)
      S[ti][tj] = __builtin_amdgcn_mfma_f32_16x16x32_bf16(qf[ti], kf[tj], S[ti][tj], 0, 0, 0);

  int catx[4], caty[4], catz[4];
  #pragma unroll
  for (int a = 0; a < 4; ++a) {
    catx[a] = (gx < 7) ? 0 : ((a < 2) ? 1 : 2);
    caty[a] = (gy < 7) ? 0 : ((a < 2) ? 1 : 2);
    catz[a] = (gz < 7) ? 0 : ((a < 2) ? 1 : 2);
  }
  const int cy = (m >> 2) & 3, cz = m & 3;
  int labc[4], labr[16];
  #pragma unroll
  for (int tj = 0; tj < 4; ++tj) labc[tj] = catx[tj] * 9 + caty[cy] * 3 + catz[cz];
  #pragma unroll
  for (int ti = 0; ti < 4; ++ti)
    #pragma unroll
    for (int r = 0; r < 4; ++r) labr[ti * 4 + r] = catx[ti] * 9 + caty[q4] * 3 + catz[r];

  #pragma unroll
  for (int ti = 0; ti < 4; ++ti)
    #pragma unroll
    for (int tj = 0; tj < 4; ++tj) {
      int K0 = 11 * (ti - tj + 3) + (q4 + 3 - cy) + (3 - cz);
      #pragma unroll
      for (int r = 0; r < 4; ++r) {
        float v = S[ti][tj][r] + bias_s[wv][K0 + r];
        if (labr[ti * 4 + r] != labc[tj]) v -= 100.f;
        S[ti][tj][r] = v;
      }
    }

  float mx[16], sm[16];
  #pragma unroll
  for (int ti = 0; ti < 4; ++ti)
    #pragma unroll
    for (int r = 0; r < 4; ++r)
      mx[ti * 4 + r] = fmaxf(fmaxf(S[ti][0][r], S[ti][1][r]), fmaxf(S[ti][2][r], S[ti][3][r]));
  #pragma unroll
  for (int off = 1; off < 16; off <<= 1)
    #pragma unroll
    for (int i = 0; i < 16; ++i) mx[i] = fmaxf(mx[i], __shfl_xor(mx[i], off, 64));
  #pragma unroll
  for (int ti = 0; ti < 4; ++ti)
    #pragma unroll
    for (int r = 0; r < 4; ++r) {
      float e0 = __expf(S[ti][0][r] - mx[ti * 4 + r]);
      float e1 = __expf(S[ti][1][r] - mx[ti * 4 + r]);
      float e2 = __expf(S[ti][2][r] - mx[ti * 4 + r]);
      float e3 = __expf(S[ti][3][r] - mx[ti * 4 + r]);
      S[ti][0][r] = e0; S[ti][1][r] = e1; S[ti][2][r] = e2; S[ti][3][r] = e3;
      sm[ti * 4 + r] = (e0 + e1) + (e2 + e3);
    }
  #pragma unroll
  for (int off = 1; off < 16; off <<= 1)
    #pragma unroll
    for (int i = 0; i < 16; ++i) sm[i] += __shfl_xor(sm[i], off, 64);
  #pragma unroll
  for (int i = 0; i < 16; ++i) sm[i] = 1.f / sm[i];

  #pragma unroll
  for (int ti = 0; ti < 4; ++ti)
    #pragma unroll
    for (int tj = 0; tj < 4; ++tj)
      #pragma unroll
      for (int r = 0; r < 4; ++r)
        P_s[wv][ti * 16 + q4 * 4 + r][tj * 16 + m] = f2bf(S[ti][tj][r]);

  f32x4 O[4][2];
  #pragma unroll
  for (int ti = 0; ti < 4; ++ti)
    #pragma unroll
    for (int tv = 0; tv < 2; ++tv) O[ti][tv] = zero;
  #pragma unroll
  for (int ks = 0; ks < 2; ++ks) {
    short8 pa[4], vb[2];
    #pragma unroll
    for (int ti = 0; ti < 4; ++ti)
      pa[ti] = *(const short8*)&P_s[wv][ti * 16 + m][ks * 32 + q4 * 8];
    #pragma unroll
    for (int tv = 0; tv < 2; ++tv)
      vb[tv] = *(const short8*)&Vt_s[wv][tv * 16 + m][ks * 32 + q4 * 8];
    #pragma unroll
    for (int ti = 0; ti < 4; ++ti)
      #pragma unroll
      for (int tv = 0; tv < 2; ++tv)
        O[ti][tv] = __builtin_amdgcn_mfma_f32_16x16x32_bf16(pa[ti], vb[tv], O[ti][tv], 0, 0, 0);
  }

  #pragma unroll
  for (int ti = 0; ti < 4; ++ti)
    #pragma unroll
    for (int tv = 0; tv < 2; ++tv)
      #pragma unroll
      for (int r = 0; r < 4; ++r) {
        int n = ti * 16 + q4 * 4 + r;
        att[(base + n) * 128 + wv * 32 + tv * 16 + m] = f2bf(O[ti][tv][r] * sm[ti * 4 + r]);
      }
}

// ---------------- proj GEMM + reverse-partition/unshift scatter + 0.5*out + inputs -> x (fp32) ----------------
__global__ __launch_bounds__(256) void k_proj(const u16* __restrict__ att,
                                              const u16* __restrict__ wT,
                                              const float* __restrict__ proj_b,
                                              const float* __restrict__ inputs,
                                              float* __restrict__ xws) {
  __shared__ __align__(16) u16 A_s[64 * 136];
  __shared__ __align__(16) u16 B_s[128 * 136];
  const int t = threadIdx.x, wid = t >> 6, lane = t & 63;
  const size_t mbase = (size_t)blockIdx.x * 64;
  {
    int r = t >> 2, seg = t & 3;
    const short8* src = (const short8*)(att + (mbase + r) * 128 + seg * 32);
    short8* dst = (short8*)(A_s + r * 136 + seg * 32);
    #pragma unroll
    for (int i = 0; i < 4; ++i) dst[i] = src[i];
  }
  {
    int r = t >> 1, half = t & 1;
    const short8* src = (const short8*)(wT + (size_t)r * 128 + half * 64);
    short8* dst = (short8*)(B_s + r * 136 + half * 64);
    #pragma unroll
    for (int i = 0; i < 8; ++i) dst[i] = src[i];
  }
  __syncthreads();
  f32x4 zero = {0.f, 0.f, 0.f, 0.f};
  f32x4 acc[2][4];
  #pragma unroll
  for (int tm = 0; tm < 2; ++tm)
    #pragma unroll
    for (int tn = 0; tn < 4; ++tn) acc[tm][tn] = zero;
  mfma_64x128(A_s, B_s, acc, wid, lane);
  const int m = lane & 15, kg = lane >> 4;
  const int ro = (wid & 1) * 32, co = (wid >> 1) * 64;
  #pragma unroll
  for (int tm = 0; tm < 2; ++tm)
    #pragma unroll
    for (int r = 0; r < 4; ++r) {
      int row = ro + tm * 16 + kg * 4 + r;
      size_t o = mbase + row;
      int nn = (int)(o & 63), wbox = (int)((o >> 6) & 511), bb = (int)(o >> 15);
      int gx = wbox >> 6, gy = (wbox >> 3) & 7, gz = wbox & 7;
      int ix = nn >> 4, iy = (nn >> 2) & 3, iz = nn & 3;
      int X = (gx * 4 + ix + 2) & 31, Y = (gy * 4 + iy + 2) & 31, Z = (gz * 4 + iz + 2) & 31;
      size_t orig = ((size_t)bb << 15) + (size_t)(X * 1024 + Y * 32 + Z);
      #pragma unroll
      for (int tn = 0; tn < 4; ++tn) {
        int col = co + tn * 16 + m;
        float v = acc[tm][tn][r] + proj_b[col];
        xws[orig * 128 + col] = 0.5f * v + inputs[orig * 128 + col];
      }
    }
}

// ---------------- fused LN2 + MLP, R3: register-resident loop ----------------
// R2 post-mortem: VGPR=88 proved the compiler rematerialized af[4][4] (64 regs) from LDS
// every iteration -> the loop chain was LDS-latency-bound. R3:
//   * __launch_bounds__(256,2): VGPR cap 256 -> af, acc, W-prefetch all stay in registers.
//   * 2-deep W1 prefetch (even/odd reg buffers), refilled POST-barrier so the barrier's
//     vmcnt(0) drain never waits on them (m97 lesson). W2 1-deep, issued pre-barrier
//     (drain absorbed by barrier arrival).
//   * bias1 values preloaded for all 8 nt.
//   * LDS 35840 -> 19456: H0/H1 overlay the dead A_s region (extra prologue barrier).
__global__ __launch_bounds__(256, 2) void k_mlp(const float* __restrict__ x,
                                                const u16* __restrict__ w1T,
                                                const u16* __restrict__ w2T,
                                                const float* __restrict__ g2,
                                                const float* __restrict__ b2,
                                                const float* __restrict__ bb1,
                                                const float* __restrict__ bb2,
                                                float* __restrict__ out) {
  __shared__ __align__(16) char lds[19456];
  u16* A_s = (u16*)lds;                       // [64][136] prologue only
  float* red = (float*)(lds + 17408);         // [64][8] prologue only
  u16* H0  = (u16*)lds;                       // [64][72] loop overlay on A_s
  u16* H1  = (u16*)(lds + 9216);              // [64][72]

  const int t = threadIdx.x, wid = t >> 6, lane = t & 63;
  const int m = lane & 15, q4 = lane >> 4;
  const size_t mbase = (size_t)blockIdx.x * 64;

  // ---- W1 prefetch, 2-deep (b1p0 = even nt, b1p1 = odd nt) ----
  const u16* w1base = w1T + (size_t)(wid * 16 + m) * 128 + q4 * 8;
  short8 b1p0[4], b1p1[4];
  #pragma unroll
  for (int kc = 0; kc < 4; ++kc) b1p0[kc] = *(const short8*)(w1base + kc * 32);
  #pragma unroll
  for (int kc = 0; kc < 4; ++kc) b1p1[kc] = *(const short8*)(w1base + (size_t)64 * 128 + kc * 32);

  // ---- preload GELU biases for all 8 nt ----
  float bias1[8];
  #pragma unroll
  for (int nt = 0; nt < 8; ++nt) bias1[nt] = bb1[nt * 64 + wid * 16 + m];

  // ---- LN2 (red overlay; disjoint from A_s) ----
  {
    int r1 = t >> 2, seg = t & 3;
    const float4* x4 = (const float4*)(x + (mbase + r1) * 128 + seg * 32);
    float vals[32];
    float s = 0.f, ss = 0.f;
    #pragma unroll
    for (int i = 0; i < 8; ++i) {
      float4 v = x4[i];
      vals[4 * i] = v.x; vals[4 * i + 1] = v.y; vals[4 * i + 2] = v.z; vals[4 * i + 3] = v.w;
      s += v.x + v.y + v.z + v.w;
      ss += v.x * v.x + v.y * v.y + v.z * v.z + v.w * v.w;
    }
    red[r1 * 8 + seg] = s; red[r1 * 8 + 4 + seg] = ss;
    float sum = red[r1 * 8 + 0] + red[r1 * 8 + 1] + red[r1 * 8 + 2] + red[r1 * 8 + 3];
    float sq  = red[r1 * 8 + 4] + red[r1 * 8 + 5] + red[r1 * 8 + 6] + red[r1 * 8 + 7];
    float mean = sum * 0.0078125f;
    float var = sq * 0.0078125f - mean * mean;
    float rs = rsqrtf(var + 1e-5f);
    #pragma unroll
    for (int i = 0; i < 32; ++i) {
      int c = seg * 32 + i;
      A_s[r1 * 136 + c] = f2bf((vals[i] - mean) * rs * g2[c] + b2[c]);
    }
  }
  __syncthreads();   // A_s complete

  // ---- ALL 64 rows of A -> registers (register-resident under (256,2)) ----
  short8 af[4][4];   // [kc][mt]
  #pragma unroll
  for (int kc = 0; kc < 4; ++kc)
    #pragma unroll
    for (int mt = 0; mt < 4; ++mt)
      af[kc][mt] = *(const short8*)(A_s + (mt * 16 + m) * 136 + kc * 32 + q4 * 8);
  __syncthreads();   // all af reads done -> A_s region reusable as H0

  f32x4 zero = {0.f, 0.f, 0.f, 0.f};
  f32x4 acc[4][2];   // [mt][nt2]: rows 16mt+4q4+r, cols 32*wid+16*nt2+m
  #pragma unroll
  for (int mt = 0; mt < 4; ++mt)
    #pragma unroll
    for (int nt2 = 0; nt2 < 2; ++nt2) acc[mt][nt2] = zero;

  #pragma unroll
  for (int nt = 0; nt < 8; ++nt) {
    u16* Hb = (nt & 1) ? H1 : H0;
    // ---- GEMM1: H[64][16*wid..+16] = A @ W1-slice (all reg operands) ----
    f32x4 hacc[4];
    #pragma unroll
    for (int mt = 0; mt < 4; ++mt) hacc[mt] = zero;
    if (nt & 1) {
      #pragma unroll
      for (int kc = 0; kc < 4; ++kc)
        #pragma unroll
        for (int mt = 0; mt < 4; ++mt)
          hacc[mt] = __builtin_amdgcn_mfma_f32_16x16x32_bf16(af[kc][mt], b1p1[kc], hacc[mt], 0, 0, 0);
    } else {
      #pragma unroll
      for (int kc = 0; kc < 4; ++kc)
        #pragma unroll
        for (int mt = 0; mt < 4; ++mt)
          hacc[mt] = __builtin_amdgcn_mfma_f32_16x16x32_bf16(af[kc][mt], b1p0[kc], hacc[mt], 0, 0, 0);
    }

    // ---- issue this iter's W2 slice (latency under GELU; drained at barrier) ----
    short8 b2f[2][2];  // [kc2][nt2]
    #pragma unroll
    for (int kc2 = 0; kc2 < 2; ++kc2)
      #pragma unroll
      for (int nt2 = 0; nt2 < 2; ++nt2)
        b2f[kc2][nt2] = *(const short8*)(w2T + (size_t)(wid * 32 + nt2 * 16 + m) * 512 +
                                         nt * 64 + kc2 * 32 + q4 * 8);

    // ---- GELU + bias -> H (wave's 16 cols) ----
    float bias = bias1[nt];
    #pragma unroll
    for (int mt = 0; mt < 4; ++mt)
      #pragma unroll
      for (int r = 0; r < 4; ++r) {
        float v = hacc[mt][r] + bias;
        float v2 = v * v;
        float qe = v * __builtin_fmaf(-0.07135482f, v2, -1.5957691f);
        float te = __expf(qe);
        float gl = v * __builtin_amdgcn_rcpf(1.f + te);
        Hb[(mt * 16 + q4 * 4 + r) * 72 + wid * 16 + m] = f2bf(gl);
      }
    __syncthreads();   // H tile complete (drains b2f: consumed immediately below)

    // ---- refill consumed W1 buffer with nt+2 (POST-barrier: never drained early) ----
    if (nt < 6) {
      const u16* p = w1base + (size_t)(nt + 2) * 64 * 128;
      if (nt & 1) {
        #pragma unroll
        for (int kc = 0; kc < 4; ++kc) b1p1[kc] = *(const short8*)(p + kc * 32);
      } else {
        #pragma unroll
        for (int kc = 0; kc < 4; ++kc) b1p0[kc] = *(const short8*)(p + kc * 32);
      }
    }

    // ---- GEMM2: out[64][32*wid..+32] += H @ W2-slice ----
    #pragma unroll
    for (int kc2 = 0; kc2 < 2; ++kc2) {
      short8 a2[4];
      #pragma unroll
      for (int mt = 0; mt < 4; ++mt)
        a2[mt] = *(const short8*)(Hb + (mt * 16 + m) * 72 + kc2 * 32 + q4 * 8);
      #pragma unroll
      for (int mt = 0; mt < 4; ++mt)
        #pragma unroll
        for (int nt2 = 0; nt2 < 2; ++nt2)
          acc[mt][nt2] = __builtin_amdgcn_mfma_f32_16x16x32_bf16(a2[mt], b2f[kc2][nt2],
                                                                 acc[mt][nt2], 0, 0, 0);
    }
  }

  // ---- epilogue: 0.5*mlp + x ----
  #pragma unroll
  for (int mt = 0; mt < 4; ++mt)
    #pragma unroll
    for (int nt2 = 0; nt2 < 2; ++nt2)
      #pragma unroll
      for (int r = 0; r < 4; ++r) {
        size_t tok = mbase + mt * 16 + q4 * 4 + r;
        int col = wid * 32 + nt2 * 16 + m;
        float v = acc[mt][nt2][r] + bb2[col];
        out[tok * 128 + col] = 0.5f * v + x[tok * 128 + col];
      }
}

extern "C" void kernel_launch(void* const* d_in, const int* in_sizes, int n_in,
                              void* d_out, int out_size, void* d_ws, size_t ws_size,
                              hipStream_t stream) {
  const float* inputs = (const float*)d_in[0];
  const float* qkv_w  = (const float*)d_in[1];
  const float* proj_w = (const float*)d_in[2];
  const float* proj_b = (const float*)d_in[3];
  const float* btab   = (const float*)d_in[4];
  const float* g1     = (const float*)d_in[5];
  const float* b1     = (const float*)d_in[6];
  const float* g2     = (const float*)d_in[7];
  const float* b2     = (const float*)d_in[8];
  const float* w1     = (const float*)d_in[9];
  const float* bb1    = (const float*)d_in[10];
  const float* w2     = (const float*)d_in[11];
  const float* bb2    = (const float*)d_in[12];
  float* out = (float*)d_out;

  char* ws = (char*)d_ws;
  u16* qkvT  = (u16*)(ws + 0);          // 384*128 bf16
  u16* projT = (u16*)(ws + 98304);      // 128*128
  u16* w1T   = (u16*)(ws + 131072);     // 512*128
  u16* w2T   = (u16*)(ws + 262144);     // 128*512
  u16* lnb   = (u16*)(ws + 393216);     // T*128 bf16 (reused as attn_out)
  u16* qkv   = (u16*)(ws + 393216 + 67108864);  // T*384 bf16 (reused as x fp32)
  u16* att   = lnb;                     // overlay: lnb dead after k_qkv
  float* xws = (float*)qkv;             // overlay: qkv dead after k_attn

  k_wprep<<<192, 256, 0, stream>>>(qkv_w, qkvT, 128, 384);
  k_wprep<<<64, 256, 0, stream>>>(proj_w, projT, 128, 128);
  k_wprep<<<256, 256, 0, stream>>>(w1, w1T, 128, 512);
  k_wprep<<<256, 256, 0, stream>>>(w2, w2T, 512, 128);

  k_ln1<<<65536, 256, 0, stream>>>(inputs, g1, b1, lnb);
  k_qkv<<<dim3(4096, 3), 256, 0, stream>>>(lnb, qkvT, qkv);
  k_attn<<<4096, 256, 0, stream>>>(qkv, btab, att);
  k_proj<<<4096, 256, 0, stream>>>(att, projT, proj_b, inputs, xws);
  k_mlp<<<4096, 256, 0, stream>>>(xws, w1T, w2T, g2, b2, bb1, bb2, out);
}

// Round 4
// 509.805 us; speedup vs baseline: 1.3303x; 1.2949x over previous
//
#include <hip/hip_runtime.h>
#include <hip/hip_bf16.h>

typedef unsigned short u16;
typedef unsigned int u32;
typedef __attribute__((ext_vector_type(8))) short short8;
typedef __attribute__((ext_vector_type(4))) float f32x4;

__device__ __forceinline__ u16 f2bf(float x) {
  __hip_bfloat16 h = __float2bfloat16(x);
  return *reinterpret_cast<u16*>(&h);
}

// ---------------- weight transpose + cast: dst[n*K+k] = bf16(src[k*N+n]) ----------------
__global__ void k_wprep(const float* __restrict__ src, u16* __restrict__ dst, int K, int N) {
  int idx = blockIdx.x * 256 + threadIdx.x;
  if (idx >= K * N) return;
  int k = idx / N, n = idx - k * N;
  dst[n * K + k] = f2bf(src[idx]);
}

// ---------------- R4: fully fused LN1 + QKV + window-attention + proj + scatter ----------------
// Replaces k_ln1/k_qkv/k_attn/k_proj. One block = one window (64 tokens, 4 waves = 4 heads).
// Eliminates lnb/qkv/att global intermediates (~830 MB of HBM round-trips).
// LDS (76800 B, 2 blocks/CU), with overlays:
//   [0,19456)      A_s  [64][152]  LN output           (dead after af reads)
//   [19456,36864)  Q_s  [64][136]                      (dead after qf reads)
//   [0,36864)      P_s  [4][64][72] overlays A_s+Q_s   (written after barrier 2)
//   [36864,54272)  K_s  [64][136]                      (dead after kf reads)
//   [36864,54272)  O_s  [64][136]  overlays K_s        (written after barrier 2)
//   [54272,72704)  Vt_s [4][32][72]
//   [72704,74752)  bias_s [4][128]
//   [74752,76800)  red  [64][8]    (LN partials)
// All padded strides (152/136/72 u16) are 16B-aligned for short8 and bank-conflict-free
// (stride mod 32 banks in {4,8,12} -> <=2 lanes/bank for 16-lane groups).
// Barriers: (1) A_s ready; (2) all A/Q/K reads done -> P/O overlays writable; (3) O_s ready.
__global__ __launch_bounds__(256, 2) void k_fused(const float* __restrict__ inputs,
                                                  const u16* __restrict__ qkvT,
                                                  const u16* __restrict__ projT,
                                                  const float* __restrict__ proj_b,
                                                  const float* __restrict__ btab,
                                                  const float* __restrict__ g1,
                                                  const float* __restrict__ b1,
                                                  float* __restrict__ xws) {
  __shared__ __align__(16) char lds[76800];
  u16* A_s  = (u16*)lds;                    // [64][152]
  u16* Q_s  = (u16*)(lds + 19456);          // [64][136]
  u16* K_s  = (u16*)(lds + 36864);          // [64][136]
  u16* P_s  = (u16*)lds;                    // [4][64][72]
  u16* O_s  = (u16*)(lds + 36864);          // [64][136]
  u16* Vt_s = (u16*)(lds + 54272);          // [4][32][72]
  float* bias_s = (float*)(lds + 72704);    // [4][128]
  float* red    = (float*)(lds + 74752);    // [64][8]

  const int t = threadIdx.x, wv = t >> 6, lane = t & 63;
  const int m = lane & 15, q4 = lane >> 4;
  const int bw = blockIdx.x;
  const int wbox = bw & 511, bsm = bw >> 9;
  const int gx = wbox >> 6, gy = (wbox >> 3) & 7, gz = wbox & 7;

  // ---- bias table -> LDS (own region, no overlay) ----
  for (int i = t; i < 484; i += 256) bias_s[(i & 3) * 128 + (i >> 2)] = btab[i];

  // ---- prefetch Q-weight fragments (L2-hot; latency hides under LN) ----
  short8 bq[4][2];
  #pragma unroll
  for (int kc = 0; kc < 4; ++kc)
    #pragma unroll
    for (int nt2 = 0; nt2 < 2; ++nt2)
      bq[kc][nt2] = *(const short8*)(qkvT + (size_t)(wv * 32 + nt2 * 16 + m) * 128 + kc * 32 + q4 * 8);

  // ---- LN1 with roll/partition gather (row r1 of this window) ----
  {
    const int r1 = t >> 2, seg = t & 3;
    const int ix = r1 >> 4, iy = (r1 >> 2) & 3, iz = r1 & 3;
    const int X = (gx * 4 + ix + 2) & 31, Y = (gy * 4 + iy + 2) & 31, Z = (gz * 4 + iz + 2) & 31;
    const size_t orig = ((size_t)bsm << 15) + (size_t)(X * 1024 + Y * 32 + Z);
    const float4* x4 = (const float4*)(inputs + orig * 128 + seg * 32);
    float vals[32];
    float s = 0.f, ss = 0.f;
    #pragma unroll
    for (int i = 0; i < 8; ++i) {
      float4 v = x4[i];
      vals[4 * i] = v.x; vals[4 * i + 1] = v.y; vals[4 * i + 2] = v.z; vals[4 * i + 3] = v.w;
      s += v.x + v.y + v.z + v.w;
      ss += v.x * v.x + v.y * v.y + v.z * v.z + v.w * v.w;
    }
    red[r1 * 8 + seg] = s; red[r1 * 8 + 4 + seg] = ss;   // same-wave 4-thread group
    float sum = red[r1 * 8 + 0] + red[r1 * 8 + 1] + red[r1 * 8 + 2] + red[r1 * 8 + 3];
    float sq  = red[r1 * 8 + 4] + red[r1 * 8 + 5] + red[r1 * 8 + 6] + red[r1 * 8 + 7];
    float mean = sum * 0.0078125f;
    float var = sq * 0.0078125f - mean * mean;
    float rs = rsqrtf(var + 1e-5f);
    #pragma unroll
    for (int i = 0; i < 32; ++i) {
      int c = seg * 32 + i;
      A_s[r1 * 152 + c] = f2bf((vals[i] - mean) * rs * g1[c] + b1[c]);
    }
  }
  __syncthreads();   // (1) A_s complete

  // ---- issue K-weight fragments (hide under af reads + Q GEMM) ----
  short8 bk[4][2];
  #pragma unroll
  for (int kc = 0; kc < 4; ++kc)
    #pragma unroll
    for (int nt2 = 0; nt2 < 2; ++nt2)
      bk[kc][nt2] = *(const short8*)(qkvT + (size_t)(128 + wv * 32 + nt2 * 16 + m) * 128 + kc * 32 + q4 * 8);

  // ---- A fragments (all 64 rows; K=128) ----
  short8 af[4][4];   // [kc][mt]
  #pragma unroll
  for (int kc = 0; kc < 4; ++kc)
    #pragma unroll
    for (int mt = 0; mt < 4; ++mt)
      af[kc][mt] = *(const short8*)(A_s + (mt * 16 + m) * 152 + kc * 32 + q4 * 8);

  f32x4 zero = {0.f, 0.f, 0.f, 0.f};

  // ---- Q GEMM: wave wv computes Q[:, 32wv..+32] ----
  {
    f32x4 acc1[4][2];
    #pragma unroll
    for (int mt = 0; mt < 4; ++mt)
      #pragma unroll
      for (int nt2 = 0; nt2 < 2; ++nt2) acc1[mt][nt2] = zero;
    #pragma unroll
    for (int kc = 0; kc < 4; ++kc)
      #pragma unroll
      for (int mt = 0; mt < 4; ++mt)
        #pragma unroll
        for (int nt2 = 0; nt2 < 2; ++nt2)
          acc1[mt][nt2] = __builtin_amdgcn_mfma_f32_16x16x32_bf16(af[kc][mt], bq[kc][nt2], acc1[mt][nt2], 0, 0, 0);
    #pragma unroll
    for (int mt = 0; mt < 4; ++mt)
      #pragma unroll
      for (int nt2 = 0; nt2 < 2; ++nt2)
        #pragma unroll
        for (int r = 0; r < 4; ++r)
          Q_s[(mt * 16 + q4 * 4 + r) * 136 + wv * 32 + nt2 * 16 + m] =
              f2bf(acc1[mt][nt2][r] * 0.17677669529663687f);   // q * HD^-0.5
  }

  // ---- issue V-weight fragments (hide under K GEMM) ----
  short8 bv[4][2];
  #pragma unroll
  for (int kc = 0; kc < 4; ++kc)
    #pragma unroll
    for (int nt2 = 0; nt2 < 2; ++nt2)
      bv[kc][nt2] = *(const short8*)(qkvT + (size_t)(256 + wv * 32 + nt2 * 16 + m) * 128 + kc * 32 + q4 * 8);

  // ---- K GEMM ----
  {
    f32x4 acc1[4][2];
    #pragma unroll
    for (int mt = 0; mt < 4; ++mt)
      #pragma unroll
      for (int nt2 = 0; nt2 < 2; ++nt2) acc1[mt][nt2] = zero;
    #pragma unroll
    for (int kc = 0; kc < 4; ++kc)
      #pragma unroll
      for (int mt = 0; mt < 4; ++mt)
        #pragma unroll
        for (int nt2 = 0; nt2 < 2; ++nt2)
          acc1[mt][nt2] = __builtin_amdgcn_mfma_f32_16x16x32_bf16(af[kc][mt], bk[kc][nt2], acc1[mt][nt2], 0, 0, 0);
    #pragma unroll
    for (int mt = 0; mt < 4; ++mt)
      #pragma unroll
      for (int nt2 = 0; nt2 < 2; ++nt2)
        #pragma unroll
        for (int r = 0; r < 4; ++r)
          K_s[(mt * 16 + q4 * 4 + r) * 136 + wv * 32 + nt2 * 16 + m] = f2bf(acc1[mt][nt2][r]);
  }

  // ---- V GEMM -> Vt_s (transposed: [d][key]) ----
  {
    f32x4 acc1[4][2];
    #pragma unroll
    for (int mt = 0; mt < 4; ++mt)
      #pragma unroll
      for (int nt2 = 0; nt2 < 2; ++nt2) acc1[mt][nt2] = zero;
    #pragma unroll
    for (int kc = 0; kc < 4; ++kc)
      #pragma unroll
      for (int mt = 0; mt < 4; ++mt)
        #pragma unroll
        for (int nt2 = 0; nt2 < 2; ++nt2)
          acc1[mt][nt2] = __builtin_amdgcn_mfma_f32_16x16x32_bf16(af[kc][mt], bv[kc][nt2], acc1[mt][nt2], 0, 0, 0);
    #pragma unroll
    for (int mt = 0; mt < 4; ++mt)
      #pragma unroll
      for (int nt2 = 0; nt2 < 2; ++nt2)
        #pragma unroll
        for (int r = 0; r < 4; ++r)
          Vt_s[wv * 2304 + (nt2 * 16 + m) * 72 + mt * 16 + q4 * 4 + r] = f2bf(acc1[mt][nt2][r]);
  }

  // ---- attention fragments (wave-private: own head's cols) ----
  short8 qf[4], kf[4];
  #pragma unroll
  for (int ti = 0; ti < 4; ++ti) {
    qf[ti] = *(const short8*)(Q_s + (ti * 16 + m) * 136 + wv * 32 + q4 * 8);
    kf[ti] = *(const short8*)(K_s + (ti * 16 + m) * 136 + wv * 32 + q4 * 8);
  }
  __syncthreads();   // (2) all A/Q/K LDS reads done across waves -> P/O overlays writable

  f32x4 S[4][4];
  #pragma unroll
  for (int ti = 0; ti < 4; ++ti)
    #pragma unroll
    for (int tj = 0; tj < 4; ++tj) S[ti][tj] = zero;
  #pragma unroll
  for (int ti = 0; ti < 4; ++ti)
    #pragma unroll
    for (int tj = 0; tj < 4; ++tj)
      S[ti][tj] = __builtin_amdgcn_mfma_f32_16x16x32_bf16(qf[ti], kf[tj], S[ti][tj], 0, 0, 0);

  int catx[4], caty[4], catz[4];
  #pragma unroll
  for (int a = 0; a < 4; ++a) {
    catx[a] = (gx < 7) ? 0 : ((a < 2) ? 1 : 2);
    caty[a] = (gy < 7) ? 0 : ((a < 2) ? 1 : 2);
    catz[a] = (gz < 7) ? 0 : ((a < 2) ? 1 : 2);
  }
  const int cy = (m >> 2) & 3, cz = m & 3;
  int labc[4], labr[16];
  #pragma unroll
  for (int tj = 0; tj < 4; ++tj) labc[tj] = catx[tj] * 9 + caty[cy] * 3 + catz[cz];
  #pragma unroll
  for (int ti = 0; ti < 4; ++ti)
    #pragma unroll
    for (int r = 0; r < 4; ++r) labr[ti * 4 + r] = catx[ti] * 9 + caty[q4] * 3 + catz[r];

  #pragma unroll
  for (int ti = 0; ti < 4; ++ti)
    #pragma unroll
    for (int tj = 0; tj < 4; ++tj) {
      int K0 = 11 * (ti - tj + 3) + (q4 + 3 - cy) + (3 - cz);
      #pragma unroll
      for (int r = 0; r < 4; ++r) {
        float v = S[ti][tj][r] + bias_s[wv * 128 + K0 + r];
        if (labr[ti * 4 + r] != labc[tj]) v -= 100.f;
        S[ti][tj][r] = v;
      }
    }

  float mx[16], sm[16];
  #pragma unroll
  for (int ti = 0; ti < 4; ++ti)
    #pragma unroll
    for (int r = 0; r < 4; ++r)
      mx[ti * 4 + r] = fmaxf(fmaxf(S[ti][0][r], S[ti][1][r]), fmaxf(S[ti][2][r], S[ti][3][r]));
  #pragma unroll
  for (int off = 1; off < 16; off <<= 1)
    #pragma unroll
    for (int i = 0; i < 16; ++i) mx[i] = fmaxf(mx[i], __shfl_xor(mx[i], off, 64));
  #pragma unroll
  for (int ti = 0; ti < 4; ++ti)
    #pragma unroll
    for (int r = 0; r < 4; ++r) {
      float e0 = __expf(S[ti][0][r] - mx[ti * 4 + r]);
      float e1 = __expf(S[ti][1][r] - mx[ti * 4 + r]);
      float e2 = __expf(S[ti][2][r] - mx[ti * 4 + r]);
      float e3 = __expf(S[ti][3][r] - mx[ti * 4 + r]);
      S[ti][0][r] = e0; S[ti][1][r] = e1; S[ti][2][r] = e2; S[ti][3][r] = e3;
      sm[ti * 4 + r] = (e0 + e1) + (e2 + e3);
    }
  #pragma unroll
  for (int off = 1; off < 16; off <<= 1)
    #pragma unroll
    for (int i = 0; i < 16; ++i) sm[i] += __shfl_xor(sm[i], off, 64);
  #pragma unroll
  for (int i = 0; i < 16; ++i) sm[i] = 1.f / sm[i];

  // ---- P -> LDS (wave-private region) ----
  #pragma unroll
  for (int ti = 0; ti < 4; ++ti)
    #pragma unroll
    for (int tj = 0; tj < 4; ++tj)
      #pragma unroll
      for (int r = 0; r < 4; ++r)
        P_s[wv * 4608 + (ti * 16 + q4 * 4 + r) * 72 + tj * 16 + m] = f2bf(S[ti][tj][r]);

  // ---- PV ----
  f32x4 O[4][2];
  #pragma unroll
  for (int ti = 0; ti < 4; ++ti)
    #pragma unroll
    for (int tv = 0; tv < 2; ++tv) O[ti][tv] = zero;
  #pragma unroll
  for (int ks = 0; ks < 2; ++ks) {
    short8 pa[4], vb[2];
    #pragma unroll
    for (int ti = 0; ti < 4; ++ti)
      pa[ti] = *(const short8*)(P_s + wv * 4608 + (ti * 16 + m) * 72 + ks * 32 + q4 * 8);
    #pragma unroll
    for (int tv = 0; tv < 2; ++tv)
      vb[tv] = *(const short8*)(Vt_s + wv * 2304 + (tv * 16 + m) * 72 + ks * 32 + q4 * 8);
    #pragma unroll
    for (int ti = 0; ti < 4; ++ti)
      #pragma unroll
      for (int tv = 0; tv < 2; ++tv)
        O[ti][tv] = __builtin_amdgcn_mfma_f32_16x16x32_bf16(pa[ti], vb[tv], O[ti][tv], 0, 0, 0);
  }

  // ---- O -> LDS (overlays K_s; K reads all done before barrier 2) ----
  #pragma unroll
  for (int ti = 0; ti < 4; ++ti)
    #pragma unroll
    for (int tv = 0; tv < 2; ++tv)
      #pragma unroll
      for (int r = 0; r < 4; ++r)
        O_s[(ti * 16 + q4 * 4 + r) * 136 + wv * 32 + tv * 16 + m] = f2bf(O[ti][tv][r] * sm[ti * 4 + r]);

  // ---- issue proj-weight fragments + bias (hide under barrier) ----
  short8 bp[4][2];
  #pragma unroll
  for (int kc = 0; kc < 4; ++kc)
    #pragma unroll
    for (int nt2 = 0; nt2 < 2; ++nt2)
      bp[kc][nt2] = *(const short8*)(projT + (size_t)(wv * 32 + nt2 * 16 + m) * 128 + kc * 32 + q4 * 8);
  float pb[2] = {proj_b[wv * 32 + m], proj_b[wv * 32 + 16 + m]};

  __syncthreads();   // (3) O_s complete

  // ---- proj GEMM: wave wv computes out cols 32wv..+32 ----
  short8 af2[4][4];
  #pragma unroll
  for (int kc = 0; kc < 4; ++kc)
    #pragma unroll
    for (int mt = 0; mt < 4; ++mt)
      af2[kc][mt] = *(const short8*)(O_s + (mt * 16 + m) * 136 + kc * 32 + q4 * 8);
  f32x4 acc2[4][2];
  #pragma unroll
  for (int mt = 0; mt < 4; ++mt)
    #pragma unroll
    for (int nt2 = 0; nt2 < 2; ++nt2) acc2[mt][nt2] = zero;
  #pragma unroll
  for (int kc = 0; kc < 4; ++kc)
    #pragma unroll
    for (int mt = 0; mt < 4; ++mt)
      #pragma unroll
      for (int nt2 = 0; nt2 < 2; ++nt2)
        acc2[mt][nt2] = __builtin_amdgcn_mfma_f32_16x16x32_bf16(af2[kc][mt], bp[kc][nt2], acc2[mt][nt2], 0, 0, 0);

  // ---- epilogue: reverse-partition/unshift scatter, 0.5*proj + inputs ----
  #pragma unroll
  for (int mt = 0; mt < 4; ++mt)
    #pragma unroll
    for (int r = 0; r < 4; ++r) {
      int nn = mt * 16 + q4 * 4 + r;
      int ix = nn >> 4, iy = (nn >> 2) & 3, iz = nn & 3;
      int X = (gx * 4 + ix + 2) & 31, Y = (gy * 4 + iy + 2) & 31, Z = (gz * 4 + iz + 2) & 31;
      size_t orig = ((size_t)bsm << 15) + (size_t)(X * 1024 + Y * 32 + Z);
      #pragma unroll
      for (int nt2 = 0; nt2 < 2; ++nt2) {
        int col = wv * 32 + nt2 * 16 + m;
        float v = acc2[mt][nt2][r] + pb[nt2];
        xws[orig * 128 + col] = 0.5f * v + inputs[orig * 128 + col];
      }
    }
}

// ---------------- fused LN2 + MLP (unchanged from R3) ----------------
__global__ __launch_bounds__(256, 2) void k_mlp(const float* __restrict__ x,
                                                const u16* __restrict__ w1T,
                                                const u16* __restrict__ w2T,
                                                const float* __restrict__ g2,
                                                const float* __restrict__ b2,
                                                const float* __restrict__ bb1,
                                                const float* __restrict__ bb2,
                                                float* __restrict__ out) {
  __shared__ __align__(16) char lds[19456];
  u16* A_s = (u16*)lds;                       // [64][136] prologue only
  float* red = (float*)(lds + 17408);         // [64][8] prologue only
  u16* H0  = (u16*)lds;                       // [64][72] loop overlay on A_s
  u16* H1  = (u16*)(lds + 9216);              // [64][72]

  const int t = threadIdx.x, wid = t >> 6, lane = t & 63;
  const int m = lane & 15, q4 = lane >> 4;
  const size_t mbase = (size_t)blockIdx.x * 64;

  const u16* w1base = w1T + (size_t)(wid * 16 + m) * 128 + q4 * 8;
  short8 b1p0[4], b1p1[4];
  #pragma unroll
  for (int kc = 0; kc < 4; ++kc) b1p0[kc] = *(const short8*)(w1base + kc * 32);
  #pragma unroll
  for (int kc = 0; kc < 4; ++kc) b1p1[kc] = *(const short8*)(w1base + (size_t)64 * 128 + kc * 32);

  float bias1[8];
  #pragma unroll
  for (int nt = 0; nt < 8; ++nt) bias1[nt] = bb1[nt * 64 + wid * 16 + m];

  {
    int r1 = t >> 2, seg = t & 3;
    const float4* x4 = (const float4*)(x + (mbase + r1) * 128 + seg * 32);
    float vals[32];
    float s = 0.f, ss = 0.f;
    #pragma unroll
    for (int i = 0; i < 8; ++i) {
      float4 v = x4[i];
      vals[4 * i] = v.x; vals[4 * i + 1] = v.y; vals[4 * i + 2] = v.z; vals[4 * i + 3] = v.w;
      s += v.x + v.y + v.z + v.w;
      ss += v.x * v.x + v.y * v.y + v.z * v.z + v.w * v.w;
    }
    red[r1 * 8 + seg] = s; red[r1 * 8 + 4 + seg] = ss;
    float sum = red[r1 * 8 + 0] + red[r1 * 8 + 1] + red[r1 * 8 + 2] + red[r1 * 8 + 3];
    float sq  = red[r1 * 8 + 4] + red[r1 * 8 + 5] + red[r1 * 8 + 6] + red[r1 * 8 + 7];
    float mean = sum * 0.0078125f;
    float var = sq * 0.0078125f - mean * mean;
    float rs = rsqrtf(var + 1e-5f);
    #pragma unroll
    for (int i = 0; i < 32; ++i) {
      int c = seg * 32 + i;
      A_s[r1 * 136 + c] = f2bf((vals[i] - mean) * rs * g2[c] + b2[c]);
    }
  }
  __syncthreads();

  short8 af[4][4];
  #pragma unroll
  for (int kc = 0; kc < 4; ++kc)
    #pragma unroll
    for (int mt = 0; mt < 4; ++mt)
      af[kc][mt] = *(const short8*)(A_s + (mt * 16 + m) * 136 + kc * 32 + q4 * 8);
  __syncthreads();

  f32x4 zero = {0.f, 0.f, 0.f, 0.f};
  f32x4 acc[4][2];
  #pragma unroll
  for (int mt = 0; mt < 4; ++mt)
    #pragma unroll
    for (int nt2 = 0; nt2 < 2; ++nt2) acc[mt][nt2] = zero;

  #pragma unroll
  for (int nt = 0; nt < 8; ++nt) {
    u16* Hb = (nt & 1) ? H1 : H0;
    f32x4 hacc[4];
    #pragma unroll
    for (int mt = 0; mt < 4; ++mt) hacc[mt] = zero;
    if (nt & 1) {
      #pragma unroll
      for (int kc = 0; kc < 4; ++kc)
        #pragma unroll
        for (int mt = 0; mt < 4; ++mt)
          hacc[mt] = __builtin_amdgcn_mfma_f32_16x16x32_bf16(af[kc][mt], b1p1[kc], hacc[mt], 0, 0, 0);
    } else {
      #pragma unroll
      for (int kc = 0; kc < 4; ++kc)
        #pragma unroll
        for (int mt = 0; mt < 4; ++mt)
          hacc[mt] = __builtin_amdgcn_mfma_f32_16x16x32_bf16(af[kc][mt], b1p0[kc], hacc[mt], 0, 0, 0);
    }

    short8 b2f[2][2];
    #pragma unroll
    for (int kc2 = 0; kc2 < 2; ++kc2)
      #pragma unroll
      for (int nt2 = 0; nt2 < 2; ++nt2)
        b2f[kc2][nt2] = *(const short8*)(w2T + (size_t)(wid * 32 + nt2 * 16 + m) * 512 +
                                         nt * 64 + kc2 * 32 + q4 * 8);

    float bias = bias1[nt];
    #pragma unroll
    for (int mt = 0; mt < 4; ++mt)
      #pragma unroll
      for (int r = 0; r < 4; ++r) {
        float v = hacc[mt][r] + bias;
        float v2 = v * v;
        float qe = v * __builtin_fmaf(-0.07135482f, v2, -1.5957691f);
        float te = __expf(qe);
        float gl = v * __builtin_amdgcn_rcpf(1.f + te);
        Hb[(mt * 16 + q4 * 4 + r) * 72 + wid * 16 + m] = f2bf(gl);
      }
    __syncthreads();

    if (nt < 6) {
      const u16* p = w1base + (size_t)(nt + 2) * 64 * 128;
      if (nt & 1) {
        #pragma unroll
        for (int kc = 0; kc < 4; ++kc) b1p1[kc] = *(const short8*)(p + kc * 32);
      } else {
        #pragma unroll
        for (int kc = 0; kc < 4; ++kc) b1p0[kc] = *(const short8*)(p + kc * 32);
      }
    }

    #pragma unroll
    for (int kc2 = 0; kc2 < 2; ++kc2) {
      short8 a2[4];
      #pragma unroll
      for (int mt = 0; mt < 4; ++mt)
        a2[mt] = *(const short8*)(Hb + (mt * 16 + m) * 72 + kc2 * 32 + q4 * 8);
      #pragma unroll
      for (int mt = 0; mt < 4; ++mt)
        #pragma unroll
        for (int nt2 = 0; nt2 < 2; ++nt2)
          acc[mt][nt2] = __builtin_amdgcn_mfma_f32_16x16x32_bf16(a2[mt], b2f[kc2][nt2],
                                                                 acc[mt][nt2], 0, 0, 0);
    }
  }

  #pragma unroll
  for (int mt = 0; mt < 4; ++mt)
    #pragma unroll
    for (int nt2 = 0; nt2 < 2; ++nt2)
      #pragma unroll
      for (int r = 0; r < 4; ++r) {
        size_t tok = mbase + mt * 16 + q4 * 4 + r;
        int col = wid * 32 + nt2 * 16 + m;
        float v = acc[mt][nt2][r] + bb2[col];
        out[tok * 128 + col] = 0.5f * v + x[tok * 128 + col];
      }
}

extern "C" void kernel_launch(void* const* d_in, const int* in_sizes, int n_in,
                              void* d_out, int out_size, void* d_ws, size_t ws_size,
                              hipStream_t stream) {
  const float* inputs = (const float*)d_in[0];
  const float* qkv_w  = (const float*)d_in[1];
  const float* proj_w = (const float*)d_in[2];
  const float* proj_b = (const float*)d_in[3];
  const float* btab   = (const float*)d_in[4];
  const float* g1     = (const float*)d_in[5];
  const float* b1     = (const float*)d_in[6];
  const float* g2     = (const float*)d_in[7];
  const float* b2     = (const float*)d_in[8];
  const float* w1     = (const float*)d_in[9];
  const float* bb1    = (const float*)d_in[10];
  const float* w2     = (const float*)d_in[11];
  const float* bb2    = (const float*)d_in[12];
  float* out = (float*)d_out;

  char* ws = (char*)d_ws;
  u16* qkvT  = (u16*)(ws + 0);          // 384*128 bf16
  u16* projT = (u16*)(ws + 98304);      // 128*128
  u16* w1T   = (u16*)(ws + 131072);     // 512*128
  u16* w2T   = (u16*)(ws + 262144);     // 128*512
  float* xws = (float*)(ws + 393216);   // T*128 fp32

  k_wprep<<<192, 256, 0, stream>>>(qkv_w, qkvT, 128, 384);
  k_wprep<<<64, 256, 0, stream>>>(proj_w, projT, 128, 128);
  k_wprep<<<256, 256, 0, stream>>>(w1, w1T, 128, 512);
  k_wprep<<<256, 256, 0, stream>>>(w2, w2T, 512, 128);

  k_fused<<<4096, 256, 0, stream>>>(inputs, qkvT, projT, proj_b, btab, g1, b1, xws);
  k_mlp<<<4096, 256, 0, stream>>>(xws, w1T, w2T, g2, b2, bb1, bb2, out);
}

// Round 5
// 481.698 us; speedup vs baseline: 1.4079x; 1.0584x over previous
//
#include <hip/hip_runtime.h>
#include <hip/hip_bf16.h>

typedef unsigned short u16;
typedef unsigned int u32;
typedef __attribute__((ext_vector_type(8))) short short8;
typedef __attribute__((ext_vector_type(4))) float f32x4;

__device__ __forceinline__ u16 f2bf(float x) {
  __hip_bfloat16 h = __float2bfloat16(x);
  return *reinterpret_cast<u16*>(&h);
}

// ---------------- R5: all 4 weight transposes in ONE launch, LDS-tiled (coalesced both sides) ----------------
__global__ __launch_bounds__(256) void k_wprep4(const float* __restrict__ qkv_w,
                                                const float* __restrict__ proj_w,
                                                const float* __restrict__ w1,
                                                const float* __restrict__ w2,
                                                u16* __restrict__ qkvT, u16* __restrict__ projT,
                                                u16* __restrict__ w1T, u16* __restrict__ w2T) {
  __shared__ float tile[64][65];
  const int b = blockIdx.x, t = threadIdx.x;
  const float* src; u16* dst; int K, N, tk, tn;
  if (b < 12)      { src = qkv_w;  dst = qkvT;  K = 128; N = 384; tk = b / 6;        tn = b % 6; }
  else if (b < 16) { src = proj_w; dst = projT; K = 128; N = 128; tk = (b - 12) / 2; tn = (b - 12) % 2; }
  else if (b < 32) { src = w1;     dst = w1T;   K = 128; N = 512; tk = (b - 16) / 8; tn = (b - 16) % 8; }
  else             { src = w2;     dst = w2T;   K = 512; N = 128; tk = (b - 32) / 2; tn = (b - 32) % 2; }
  const int rb = t >> 6, c = t & 63;
  #pragma unroll
  for (int i = 0; i < 16; ++i) {
    int r = i * 4 + rb;
    tile[r][c] = src[(size_t)(tk * 64 + r) * N + tn * 64 + c];   // coalesced read
  }
  __syncthreads();
  #pragma unroll
  for (int i = 0; i < 16; ++i) {
    int rr = i * 4 + rb;   // n-index
    dst[(size_t)(tn * 64 + rr) * K + tk * 64 + c] = f2bf(tile[c][rr]);  // coalesced write, 2-way LDS ok
  }
}

// ---------------- R5: ONE kernel per window: LN1+QKV+attn+proj+LN2+MLP ----------------
// Eliminates the xws global round-trip (~268 MB) and the grid-wide sync between k_fused/k_mlp.
// LDS (76800 B, 2 blocks/CU) with phase overlays:
//  phase 1 (attn, identical to R4 k_fused):
//   [0,19456)      A_s  [64][152]   (dead after af reads)
//   [19456,36864)  Q_s  [64][136]   (dead after qf reads)
//   [0,36864)      P_s  [4][64][72] overlay, written after barrier 2
//   [36864,54272)  K_s  [64][136] -> O_s overlay
//   [54272,72704)  Vt_s [4][32][72]
//   [72704,74752)  bias_s [4][128]
//   [74752,76800)  red  [64][8]
//  phase 2 (x + LN2 + MLP):
//   [0,33792)      X_s  [64][132] fp32  (overlays P_s; written after barrier 3)
//   [36864,54272)  A2_s [64][136]       (overlays O_s; written after barrier 4)
//   [54272,72704)  H0/H1 [64][72] x2    (overlays Vt_s; written after barrier 5)
//   [74752,76800)  red reused for LN2
// Barriers: 3 attn + 2 (X/LN2) + 8 (MLP loop) = 13.
__global__ __launch_bounds__(256, 2) void k_all(const float* __restrict__ inputs,
                                                const u16* __restrict__ qkvT,
                                                const u16* __restrict__ projT,
                                                const float* __restrict__ proj_b,
                                                const float* __restrict__ btab,
                                                const float* __restrict__ g1,
                                                const float* __restrict__ b1,
                                                const u16* __restrict__ w1T,
                                                const u16* __restrict__ w2T,
                                                const float* __restrict__ g2,
                                                const float* __restrict__ b2,
                                                const float* __restrict__ bb1,
                                                const float* __restrict__ bb2,
                                                float* __restrict__ out) {
  __shared__ __align__(16) char lds[76800];
  u16* A_s  = (u16*)lds;                    // [64][152]
  u16* Q_s  = (u16*)(lds + 19456);          // [64][136]
  u16* K_s  = (u16*)(lds + 36864);          // [64][136]
  u16* P_s  = (u16*)lds;                    // [4][64][72]
  u16* O_s  = (u16*)(lds + 36864);          // [64][136]
  u16* Vt_s = (u16*)(lds + 54272);          // [4][32][72]
  float* bias_s = (float*)(lds + 72704);    // [4][128]
  float* red    = (float*)(lds + 74752);    // [64][8]
  float* X_s = (float*)lds;                 // [64][132] fp32 (phase 2)
  u16* A2_s  = (u16*)(lds + 36864);         // [64][136]      (phase 2)
  u16* H0    = (u16*)(lds + 54272);         // [64][72]
  u16* H1    = (u16*)(lds + 63488);         // [64][72]

  const int t = threadIdx.x, wv = t >> 6, lane = t & 63;
  const int m = lane & 15, q4 = lane >> 4;
  const int bw = blockIdx.x;
  const int wbox = bw & 511, bsm = bw >> 9;
  const int gx = wbox >> 6, gy = (wbox >> 3) & 7, gz = wbox & 7;

  // ---- bias table -> LDS ----
  for (int i = t; i < 484; i += 256) bias_s[(i & 3) * 128 + (i >> 2)] = btab[i];

  // ---- prefetch Q-weight fragments ----
  short8 bq[4][2];
  #pragma unroll
  for (int kc = 0; kc < 4; ++kc)
    #pragma unroll
    for (int nt2 = 0; nt2 < 2; ++nt2)
      bq[kc][nt2] = *(const short8*)(qkvT + (size_t)(wv * 32 + nt2 * 16 + m) * 128 + kc * 32 + q4 * 8);

  // ---- LN1 with roll/partition gather ----
  {
    const int r1 = t >> 2, seg = t & 3;
    const int ix = r1 >> 4, iy = (r1 >> 2) & 3, iz = r1 & 3;
    const int X = (gx * 4 + ix + 2) & 31, Y = (gy * 4 + iy + 2) & 31, Z = (gz * 4 + iz + 2) & 31;
    const size_t orig = ((size_t)bsm << 15) + (size_t)(X * 1024 + Y * 32 + Z);
    const float4* x4 = (const float4*)(inputs + orig * 128 + seg * 32);
    float vals[32];
    float s = 0.f, ss = 0.f;
    #pragma unroll
    for (int i = 0; i < 8; ++i) {
      float4 v = x4[i];
      vals[4 * i] = v.x; vals[4 * i + 1] = v.y; vals[4 * i + 2] = v.z; vals[4 * i + 3] = v.w;
      s += v.x + v.y + v.z + v.w;
      ss += v.x * v.x + v.y * v.y + v.z * v.z + v.w * v.w;
    }
    red[r1 * 8 + seg] = s; red[r1 * 8 + 4 + seg] = ss;
    float sum = red[r1 * 8 + 0] + red[r1 * 8 + 1] + red[r1 * 8 + 2] + red[r1 * 8 + 3];
    float sq  = red[r1 * 8 + 4] + red[r1 * 8 + 5] + red[r1 * 8 + 6] + red[r1 * 8 + 7];
    float mean = sum * 0.0078125f;
    float var = sq * 0.0078125f - mean * mean;
    float rs = rsqrtf(var + 1e-5f);
    #pragma unroll
    for (int i = 0; i < 32; ++i) {
      int c = seg * 32 + i;
      A_s[r1 * 152 + c] = f2bf((vals[i] - mean) * rs * g1[c] + b1[c]);
    }
  }
  __syncthreads();   // (1) A_s complete

  short8 bk[4][2];
  #pragma unroll
  for (int kc = 0; kc < 4; ++kc)
    #pragma unroll
    for (int nt2 = 0; nt2 < 2; ++nt2)
      bk[kc][nt2] = *(const short8*)(qkvT + (size_t)(128 + wv * 32 + nt2 * 16 + m) * 128 + kc * 32 + q4 * 8);

  short8 af[4][4];
  #pragma unroll
  for (int kc = 0; kc < 4; ++kc)
    #pragma unroll
    for (int mt = 0; mt < 4; ++mt)
      af[kc][mt] = *(const short8*)(A_s + (mt * 16 + m) * 152 + kc * 32 + q4 * 8);

  f32x4 zero = {0.f, 0.f, 0.f, 0.f};

  // ---- Q GEMM ----
  {
    f32x4 acc1[4][2];
    #pragma unroll
    for (int mt = 0; mt < 4; ++mt)
      #pragma unroll
      for (int nt2 = 0; nt2 < 2; ++nt2) acc1[mt][nt2] = zero;
    #pragma unroll
    for (int kc = 0; kc < 4; ++kc)
      #pragma unroll
      for (int mt = 0; mt < 4; ++mt)
        #pragma unroll
        for (int nt2 = 0; nt2 < 2; ++nt2)
          acc1[mt][nt2] = __builtin_amdgcn_mfma_f32_16x16x32_bf16(af[kc][mt], bq[kc][nt2], acc1[mt][nt2], 0, 0, 0);
    #pragma unroll
    for (int mt = 0; mt < 4; ++mt)
      #pragma unroll
      for (int nt2 = 0; nt2 < 2; ++nt2)
        #pragma unroll
        for (int r = 0; r < 4; ++r)
          Q_s[(mt * 16 + q4 * 4 + r) * 136 + wv * 32 + nt2 * 16 + m] =
              f2bf(acc1[mt][nt2][r] * 0.17677669529663687f);
  }

  short8 bv[4][2];
  #pragma unroll
  for (int kc = 0; kc < 4; ++kc)
    #pragma unroll
    for (int nt2 = 0; nt2 < 2; ++nt2)
      bv[kc][nt2] = *(const short8*)(qkvT + (size_t)(256 + wv * 32 + nt2 * 16 + m) * 128 + kc * 32 + q4 * 8);

  // ---- K GEMM ----
  {
    f32x4 acc1[4][2];
    #pragma unroll
    for (int mt = 0; mt < 4; ++mt)
      #pragma unroll
      for (int nt2 = 0; nt2 < 2; ++nt2) acc1[mt][nt2] = zero;
    #pragma unroll
    for (int kc = 0; kc < 4; ++kc)
      #pragma unroll
      for (int mt = 0; mt < 4; ++mt)
        #pragma unroll
        for (int nt2 = 0; nt2 < 2; ++nt2)
          acc1[mt][nt2] = __builtin_amdgcn_mfma_f32_16x16x32_bf16(af[kc][mt], bk[kc][nt2], acc1[mt][nt2], 0, 0, 0);
    #pragma unroll
    for (int mt = 0; mt < 4; ++mt)
      #pragma unroll
      for (int nt2 = 0; nt2 < 2; ++nt2)
        #pragma unroll
        for (int r = 0; r < 4; ++r)
          K_s[(mt * 16 + q4 * 4 + r) * 136 + wv * 32 + nt2 * 16 + m] = f2bf(acc1[mt][nt2][r]);
  }

  // ---- V GEMM -> Vt_s ----
  {
    f32x4 acc1[4][2];
    #pragma unroll
    for (int mt = 0; mt < 4; ++mt)
      #pragma unroll
      for (int nt2 = 0; nt2 < 2; ++nt2) acc1[mt][nt2] = zero;
    #pragma unroll
    for (int kc = 0; kc < 4; ++kc)
      #pragma unroll
      for (int mt = 0; mt < 4; ++mt)
        #pragma unroll
        for (int nt2 = 0; nt2 < 2; ++nt2)
          acc1[mt][nt2] = __builtin_amdgcn_mfma_f32_16x16x32_bf16(af[kc][mt], bv[kc][nt2], acc1[mt][nt2], 0, 0, 0);
    #pragma unroll
    for (int mt = 0; mt < 4; ++mt)
      #pragma unroll
      for (int nt2 = 0; nt2 < 2; ++nt2)
        #pragma unroll
        for (int r = 0; r < 4; ++r)
          Vt_s[wv * 2304 + (nt2 * 16 + m) * 72 + mt * 16 + q4 * 4 + r] = f2bf(acc1[mt][nt2][r]);
  }

  short8 qf[4], kf[4];
  #pragma unroll
  for (int ti = 0; ti < 4; ++ti) {
    qf[ti] = *(const short8*)(Q_s + (ti * 16 + m) * 136 + wv * 32 + q4 * 8);
    kf[ti] = *(const short8*)(K_s + (ti * 16 + m) * 136 + wv * 32 + q4 * 8);
  }
  __syncthreads();   // (2) A/Q/K reads done -> P/O overlays writable

  f32x4 S[4][4];
  #pragma unroll
  for (int ti = 0; ti < 4; ++ti)
    #pragma unroll
    for (int tj = 0; tj < 4; ++tj) S[ti][tj] = zero;
  #pragma unroll
  for (int ti = 0; ti < 4; ++ti)
    #pragma unroll
    for (int tj = 0; tj < 4; ++tj)
      S[ti][tj] = __builtin_amdgcn_mfma_f32_16x16x32_bf16(qf[ti], kf[tj], S[ti][tj], 0, 0, 0);

  int catx[4], caty[4], catz[4];
  #pragma unroll
  for (int a = 0; a < 4; ++a) {
    catx[a] = (gx < 7) ? 0 : ((a < 2) ? 1 : 2);
    caty[a] = (gy < 7) ? 0 : ((a < 2) ? 1 : 2);
    catz[a] = (gz < 7) ? 0 : ((a < 2) ? 1 : 2);
  }
  const int cy = (m >> 2) & 3, cz = m & 3;
  int labc[4], labr[16];
  #pragma unroll
  for (int tj = 0; tj < 4; ++tj) labc[tj] = catx[tj] * 9 + caty[cy] * 3 + catz[cz];
  #pragma unroll
  for (int ti = 0; ti < 4; ++ti)
    #pragma unroll
    for (int r = 0; r < 4; ++r) labr[ti * 4 + r] = catx[ti] * 9 + caty[q4] * 3 + catz[r];

  #pragma unroll
  for (int ti = 0; ti < 4; ++ti)
    #pragma unroll
    for (int tj = 0; tj < 4; ++tj) {
      int K0 = 11 * (ti - tj + 3) + (q4 + 3 - cy) + (3 - cz);
      #pragma unroll
      for (int r = 0; r < 4; ++r) {
        float v = S[ti][tj][r] + bias_s[wv * 128 + K0 + r];
        if (labr[ti * 4 + r] != labc[tj]) v -= 100.f;
        S[ti][tj][r] = v;
      }
    }

  float mx[16], sm[16];
  #pragma unroll
  for (int ti = 0; ti < 4; ++ti)
    #pragma unroll
    for (int r = 0; r < 4; ++r)
      mx[ti * 4 + r] = fmaxf(fmaxf(S[ti][0][r], S[ti][1][r]), fmaxf(S[ti][2][r], S[ti][3][r]));
  #pragma unroll
  for (int off = 1; off < 16; off <<= 1)
    #pragma unroll
    for (int i = 0; i < 16; ++i) mx[i] = fmaxf(mx[i], __shfl_xor(mx[i], off, 64));
  #pragma unroll
  for (int ti = 0; ti < 4; ++ti)
    #pragma unroll
    for (int r = 0; r < 4; ++r) {
      float e0 = __expf(S[ti][0][r] - mx[ti * 4 + r]);
      float e1 = __expf(S[ti][1][r] - mx[ti * 4 + r]);
      float e2 = __expf(S[ti][2][r] - mx[ti * 4 + r]);
      float e3 = __expf(S[ti][3][r] - mx[ti * 4 + r]);
      S[ti][0][r] = e0; S[ti][1][r] = e1; S[ti][2][r] = e2; S[ti][3][r] = e3;
      sm[ti * 4 + r] = (e0 + e1) + (e2 + e3);
    }
  #pragma unroll
  for (int off = 1; off < 16; off <<= 1)
    #pragma unroll
    for (int i = 0; i < 16; ++i) sm[i] += __shfl_xor(sm[i], off, 64);
  #pragma unroll
  for (int i = 0; i < 16; ++i) sm[i] = 1.f / sm[i];

  #pragma unroll
  for (int ti = 0; ti < 4; ++ti)
    #pragma unroll
    for (int tj = 0; tj < 4; ++tj)
      #pragma unroll
      for (int r = 0; r < 4; ++r)
        P_s[wv * 4608 + (ti * 16 + q4 * 4 + r) * 72 + tj * 16 + m] = f2bf(S[ti][tj][r]);

  f32x4 O[4][2];
  #pragma unroll
  for (int ti = 0; ti < 4; ++ti)
    #pragma unroll
    for (int tv = 0; tv < 2; ++tv) O[ti][tv] = zero;
  #pragma unroll
  for (int ks = 0; ks < 2; ++ks) {
    short8 pa[4], vb[2];
    #pragma unroll
    for (int ti = 0; ti < 4; ++ti)
      pa[ti] = *(const short8*)(P_s + wv * 4608 + (ti * 16 + m) * 72 + ks * 32 + q4 * 8);
    #pragma unroll
    for (int tv = 0; tv < 2; ++tv)
      vb[tv] = *(const short8*)(Vt_s + wv * 2304 + (tv * 16 + m) * 72 + ks * 32 + q4 * 8);
    #pragma unroll
    for (int ti = 0; ti < 4; ++ti)
      #pragma unroll
      for (int tv = 0; tv < 2; ++tv)
        O[ti][tv] = __builtin_amdgcn_mfma_f32_16x16x32_bf16(pa[ti], vb[tv], O[ti][tv], 0, 0, 0);
  }

  #pragma unroll
  for (int ti = 0; ti < 4; ++ti)
    #pragma unroll
    for (int tv = 0; tv < 2; ++tv)
      #pragma unroll
      for (int r = 0; r < 4; ++r)
        O_s[(ti * 16 + q4 * 4 + r) * 136 + wv * 32 + tv * 16 + m] = f2bf(O[ti][tv][r] * sm[ti * 4 + r]);

  // ---- proj weights + bias (pre-barrier) ----
  short8 bp[4][2];
  #pragma unroll
  for (int kc = 0; kc < 4; ++kc)
    #pragma unroll
    for (int nt2 = 0; nt2 < 2; ++nt2)
      bp[kc][nt2] = *(const short8*)(projT + (size_t)(wv * 32 + nt2 * 16 + m) * 128 + kc * 32 + q4 * 8);
  float pb[2] = {proj_b[wv * 32 + m], proj_b[wv * 32 + 16 + m]};

  __syncthreads();   // (3) O_s ready; P_s region dead -> X_s writable

  // ---- proj GEMM ----
  short8 af2[4][4];
  #pragma unroll
  for (int kc = 0; kc < 4; ++kc)
    #pragma unroll
    for (int mt = 0; mt < 4; ++mt)
      af2[kc][mt] = *(const short8*)(O_s + (mt * 16 + m) * 136 + kc * 32 + q4 * 8);
  f32x4 acc2[4][2];
  #pragma unroll
  for (int mt = 0; mt < 4; ++mt)
    #pragma unroll
    for (int nt2 = 0; nt2 < 2; ++nt2) acc2[mt][nt2] = zero;
  #pragma unroll
  for (int kc = 0; kc < 4; ++kc)
    #pragma unroll
    for (int mt = 0; mt < 4; ++mt)
      #pragma unroll
      for (int nt2 = 0; nt2 < 2; ++nt2)
        acc2[mt][nt2] = __builtin_amdgcn_mfma_f32_16x16x32_bf16(af2[kc][mt], bp[kc][nt2], acc2[mt][nt2], 0, 0, 0);

  // ---- X_s = 0.5*(proj+pb)  (residual added next step, LN1-gather pattern) ----
  #pragma unroll
  for (int mt = 0; mt < 4; ++mt)
    #pragma unroll
    for (int nt2 = 0; nt2 < 2; ++nt2)
      #pragma unroll
      for (int r = 0; r < 4; ++r)
        X_s[(mt * 16 + q4 * 4 + r) * 132 + wv * 32 + nt2 * 16 + m] = 0.5f * (acc2[mt][nt2][r] + pb[nt2]);

  __syncthreads();   // (4) X_s(half) complete; O_s reads done -> A2_s writable

  // ---- x += inputs; LN2 -> A2_s; also prefetch W1 (2-deep) + biases for MLP ----
  const u16* w1base = w1T + (size_t)(wv * 16 + m) * 128 + q4 * 8;
  short8 b1p0[4], b1p1[4];
  #pragma unroll
  for (int kc = 0; kc < 4; ++kc) b1p0[kc] = *(const short8*)(w1base + kc * 32);
  #pragma unroll
  for (int kc = 0; kc < 4; ++kc) b1p1[kc] = *(const short8*)(w1base + (size_t)64 * 128 + kc * 32);
  float bias1[8];
  #pragma unroll
  for (int nt = 0; nt < 8; ++nt) bias1[nt] = bb1[nt * 64 + wv * 16 + m];

  {
    const int r1 = t >> 2, seg = t & 3;
    const int ix = r1 >> 4, iy = (r1 >> 2) & 3, iz = r1 & 3;
    const int X = (gx * 4 + ix + 2) & 31, Y = (gy * 4 + iy + 2) & 31, Z = (gz * 4 + iz + 2) & 31;
    const size_t orig = ((size_t)bsm << 15) + (size_t)(X * 1024 + Y * 32 + Z);
    const float4* x4 = (const float4*)(inputs + orig * 128 + seg * 32);
    float vals[32];
    float s = 0.f, ss = 0.f;
    #pragma unroll
    for (int i = 0; i < 8; ++i) {
      float4 v = x4[i];
      float* xp = X_s + r1 * 132 + seg * 32 + 4 * i;
      float a0 = xp[0] + v.x, a1 = xp[1] + v.y, a2 = xp[2] + v.z, a3 = xp[3] + v.w;
      xp[0] = a0; xp[1] = a1; xp[2] = a2; xp[3] = a3;
      vals[4 * i] = a0; vals[4 * i + 1] = a1; vals[4 * i + 2] = a2; vals[4 * i + 3] = a3;
      s += a0 + a1 + a2 + a3;
      ss += a0 * a0 + a1 * a1 + a2 * a2 + a3 * a3;
    }
    red[r1 * 8 + seg] = s; red[r1 * 8 + 4 + seg] = ss;
    float sum = red[r1 * 8 + 0] + red[r1 * 8 + 1] + red[r1 * 8 + 2] + red[r1 * 8 + 3];
    float sq  = red[r1 * 8 + 4] + red[r1 * 8 + 5] + red[r1 * 8 + 6] + red[r1 * 8 + 7];
    float mean = sum * 0.0078125f;
    float var = sq * 0.0078125f - mean * mean;
    float rs = rsqrtf(var + 1e-5f);
    #pragma unroll
    for (int i = 0; i < 32; ++i) {
      int c = seg * 32 + i;
      A2_s[r1 * 136 + c] = f2bf((vals[i] - mean) * rs * g2[c] + b2[c]);
    }
  }
  __syncthreads();   // (5) A2_s ready; X_s final; Vt_s dead -> H writable

  // ---- MLP (R3 structure; A from A2_s, H double-buffered, W from L2) ----
  short8 am[4][4];
  #pragma unroll
  for (int kc = 0; kc < 4; ++kc)
    #pragma unroll
    for (int mt = 0; mt < 4; ++mt)
      am[kc][mt] = *(const short8*)(A2_s + (mt * 16 + m) * 136 + kc * 32 + q4 * 8);

  f32x4 acc[4][2];
  #pragma unroll
  for (int mt = 0; mt < 4; ++mt)
    #pragma unroll
    for (int nt2 = 0; nt2 < 2; ++nt2) acc[mt][nt2] = zero;

  #pragma unroll
  for (int nt = 0; nt < 8; ++nt) {
    u16* Hb = (nt & 1) ? H1 : H0;
    f32x4 hacc[4];
    #pragma unroll
    for (int mt = 0; mt < 4; ++mt) hacc[mt] = zero;
    if (nt & 1) {
      #pragma unroll
      for (int kc = 0; kc < 4; ++kc)
        #pragma unroll
        for (int mt = 0; mt < 4; ++mt)
          hacc[mt] = __builtin_amdgcn_mfma_f32_16x16x32_bf16(am[kc][mt], b1p1[kc], hacc[mt], 0, 0, 0);
    } else {
      #pragma unroll
      for (int kc = 0; kc < 4; ++kc)
        #pragma unroll
        for (int mt = 0; mt < 4; ++mt)
          hacc[mt] = __builtin_amdgcn_mfma_f32_16x16x32_bf16(am[kc][mt], b1p0[kc], hacc[mt], 0, 0, 0);
    }

    short8 b2f[2][2];
    #pragma unroll
    for (int kc2 = 0; kc2 < 2; ++kc2)
      #pragma unroll
      for (int nt2 = 0; nt2 < 2; ++nt2)
        b2f[kc2][nt2] = *(const short8*)(w2T + (size_t)(wv * 32 + nt2 * 16 + m) * 512 +
                                         nt * 64 + kc2 * 32 + q4 * 8);

    float bias = bias1[nt];
    #pragma unroll
    for (int mt = 0; mt < 4; ++mt)
      #pragma unroll
      for (int r = 0; r < 4; ++r) {
        float v = hacc[mt][r] + bias;
        float v2 = v * v;
        float qe = v * __builtin_fmaf(-0.07135482f, v2, -1.5957691f);
        float te = __expf(qe);
        float gl = v * __builtin_amdgcn_rcpf(1.f + te);
        Hb[(mt * 16 + q4 * 4 + r) * 72 + wv * 16 + m] = f2bf(gl);
      }
    __syncthreads();

    if (nt < 6) {
      const u16* p = w1base + (size_t)(nt + 2) * 64 * 128;
      if (nt & 1) {
        #pragma unroll
        for (int kc = 0; kc < 4; ++kc) b1p1[kc] = *(const short8*)(p + kc * 32);
      } else {
        #pragma unroll
        for (int kc = 0; kc < 4; ++kc) b1p0[kc] = *(const short8*)(p + kc * 32);
      }
    }

    #pragma unroll
    for (int kc2 = 0; kc2 < 2; ++kc2) {
      short8 a2[4];
      #pragma unroll
      for (int mt = 0; mt < 4; ++mt)
        a2[mt] = *(const short8*)(Hb + (mt * 16 + m) * 72 + kc2 * 32 + q4 * 8);
      #pragma unroll
      for (int mt = 0; mt < 4; ++mt)
        #pragma unroll
        for (int nt2 = 0; nt2 < 2; ++nt2)
          acc[mt][nt2] = __builtin_amdgcn_mfma_f32_16x16x32_bf16(a2[mt], b2f[kc2][nt2],
                                                                 acc[mt][nt2], 0, 0, 0);
    }
  }

  // ---- epilogue: out[orig] = 0.5*(mlp+bb2) + x (x from LDS) ----
  float ob[2] = {bb2[wv * 32 + m], bb2[wv * 32 + 16 + m]};
  #pragma unroll
  for (int mt = 0; mt < 4; ++mt)
    #pragma unroll
    for (int r = 0; r < 4; ++r) {
      int nn = mt * 16 + q4 * 4 + r;
      int ix = nn >> 4, iy = (nn >> 2) & 3, iz = nn & 3;
      int X = (gx * 4 + ix + 2) & 31, Y = (gy * 4 + iy + 2) & 31, Z = (gz * 4 + iz + 2) & 31;
      size_t orig = ((size_t)bsm << 15) + (size_t)(X * 1024 + Y * 32 + Z);
      #pragma unroll
      for (int nt2 = 0; nt2 < 2; ++nt2) {
        int col = wv * 32 + nt2 * 16 + m;
        float v = acc[mt][nt2][r] + ob[nt2];
        out[orig * 128 + col] = 0.5f * v + X_s[nn * 132 + col];
      }
    }
}

extern "C" void kernel_launch(void* const* d_in, const int* in_sizes, int n_in,
                              void* d_out, int out_size, void* d_ws, size_t ws_size,
                              hipStream_t stream) {
  const float* inputs = (const float*)d_in[0];
  const float* qkv_w  = (const float*)d_in[1];
  const float* proj_w = (const float*)d_in[2];
  const float* proj_b = (const float*)d_in[3];
  const float* btab   = (const float*)d_in[4];
  const float* g1     = (const float*)d_in[5];
  const float* b1     = (const float*)d_in[6];
  const float* g2     = (const float*)d_in[7];
  const float* b2     = (const float*)d_in[8];
  const float* w1     = (const float*)d_in[9];
  const float* bb1    = (const float*)d_in[10];
  const float* w2     = (const float*)d_in[11];
  const float* bb2    = (const float*)d_in[12];
  float* out = (float*)d_out;

  char* ws = (char*)d_ws;
  u16* qkvT  = (u16*)(ws + 0);          // 384*128 bf16
  u16* projT = (u16*)(ws + 98304);      // 128*128
  u16* w1T   = (u16*)(ws + 131072);     // 512*128
  u16* w2T   = (u16*)(ws + 262144);     // 128*512

  k_wprep4<<<48, 256, 0, stream>>>(qkv_w, proj_w, w1, w2, qkvT, projT, w1T, w2T);
  k_all<<<4096, 256, 0, stream>>>(inputs, qkvT, projT, proj_b, btab, g1, b1,
                                  w1T, w2T, g2, b2, bb1, bb2, out);
}